// Round 3
// baseline (1499.419 us; speedup 1.0000x reference)
//
#include <hip/hip_runtime.h>
#include <cstdint>
#include <cmath>

#define NBATCH   8
#define NPB      500000
#define PRE_NMS  6000
#define POST_NMS 1000
#define NWORDS   94          // ceil(6000/64)
#define NBINS    16384       // 14-bit float prefix (sign+exp+5 mantissa)
#define CANDCAP  8192        // candidate cap per batch (expected ~6400 worst case)
#define BBOX_CLIP 4.135166556742356f   // log(1000/16)
#define NMS_THR  0.7f

#define F_SORT 1u
#define F_COMP 2u
#define F_OOB  4u

// monotone map: ascending uint <=> ascending float
__device__ __forceinline__ unsigned monot(float f) {
    unsigned b = __float_as_uint(f);
    return (b & 0x80000000u) ? ~b : (b | 0x80000000u);
}

// ---------------- Phase 1a: 16384-bin histogram of key prefix ----------------
__global__ __launch_bounds__(256) void hist_kernel(const float* __restrict__ obj,
                                                   unsigned* __restrict__ hist) {
    __shared__ unsigned lh[NBINS];   // 64 KiB
    const int b = blockIdx.y;
    for (int q = threadIdx.x; q < NBINS; q += 256) lh[q] = 0;
    __syncthreads();
    const float* p = obj + (size_t)b * NPB;
    const int stride = gridDim.x * 256;
    for (int i = blockIdx.x * 256 + threadIdx.x; i < NPB; i += stride) {
        unsigned u = monot(p[i]);
        atomicAdd(&lh[u >> 18], 1u);
    }
    __syncthreads();
    unsigned* gh = hist + (size_t)b * NBINS;
    for (int q = threadIdx.x; q < NBINS; q += 256) {
        unsigned v = lh[q];
        if (v) atomicAdd(&gh[q], v);
    }
}

// ------- Phase 1b: find threshold bin (descending cumulative >= 6000) -------
__global__ __launch_bounds__(256) void thresh_kernel(const unsigned* __restrict__ hist,
                                                     unsigned* __restrict__ tbin) {
    __shared__ unsigned part[256], pre[256];
    const int b = blockIdx.x;
    const unsigned* gh = hist + (size_t)b * NBINS;
    const int t = threadIdx.x;
    const int PER = NBINS / 256;     // 64 bins per thread
    unsigned s = 0;
    for (int d = 0; d < PER; ++d) s += gh[NBINS - 1 - (t * PER + d)];
    part[t] = s;
    __syncthreads();
    if (t == 0) {
        unsigned run = 0;
        for (int q = 0; q < 256; ++q) { pre[q] = run; run += part[q]; }
    }
    __syncthreads();
    unsigned c = pre[t];
    if (c < PRE_NMS && c + part[t] >= PRE_NMS) {
        unsigned run = c;
        for (int d = 0; d < PER; ++d) {
            int bin = NBINS - 1 - (t * PER + d);
            run += gh[bin];
            if (run >= PRE_NMS) { tbin[b] = (unsigned)bin; break; }
        }
    }
}

// ---------------- Phase 1c: compact candidates (key,idx) ----------------
__global__ __launch_bounds__(256) void compact_kernel(const float* __restrict__ obj,
                                                      const unsigned* __restrict__ tbin,
                                                      unsigned long long* __restrict__ cand,
                                                      unsigned* __restrict__ ccnt) {
    const int b = blockIdx.y;
    const unsigned T = tbin[b];
    const float* p = obj + (size_t)b * NPB;
    unsigned long long* cb = cand + (size_t)b * CANDCAP;
    const int stride = gridDim.x * 256;
    for (int i = blockIdx.x * 256 + threadIdx.x; i < NPB; i += stride) {
        unsigned u = monot(p[i]);
        if ((u >> 18) >= T) {
            unsigned pos = atomicAdd(&ccnt[b], 1u);
            if (pos < CANDCAP)  // composite: value desc, then index asc (via ~i)
                cb[pos] = ((unsigned long long)u << 32) | (unsigned)(~i);
        }
    }
}

// -------- Phase 1d: per-batch bitonic sort (descending) in 64 KiB LDS -------
// + self-verification: strict descending, composite<->input consistency.
__global__ __launch_bounds__(1024) void sort_kernel(const unsigned long long* __restrict__ cand,
                                                    const float* __restrict__ obj,
                                                    unsigned* __restrict__ topk,
                                                    unsigned long long* __restrict__ skey,
                                                    unsigned* __restrict__ flags) {
    __shared__ unsigned long long s[CANDCAP];  // 64 KiB
    const int b = blockIdx.x, t = threadIdx.x;
    const unsigned long long* cb = cand + (size_t)b * CANDCAP;
    for (int i = t; i < CANDCAP; i += 1024) s[i] = cb[i];
    __syncthreads();
    for (unsigned k = 2; k <= CANDCAP; k <<= 1) {
        for (unsigned j = k >> 1; j > 0; j >>= 1) {
            for (unsigned ii = t; ii < CANDCAP; ii += 1024) {
                unsigned l = ii ^ j;
                if (l > ii) {
                    unsigned long long a = s[ii], c = s[l];
                    bool up = (ii & k) == 0;
                    if (up ? (a < c) : (a > c)) { s[ii] = c; s[l] = a; }
                }
            }
            __syncthreads();
        }
    }
    // ---- checks + emit ----
    unsigned f = 0;
    for (int r = t; r < PRE_NMS; r += 1024) {
        unsigned long long c = s[r];
        unsigned idx = ~(unsigned)(c & 0xffffffffULL);
        if (idx >= NPB) { f |= F_OOB; idx = 0; }
        else if (monot(obj[(size_t)b * NPB + idx]) != (unsigned)(c >> 32)) f |= F_COMP;
        if (r < PRE_NMS - 1 && !(c > s[r + 1])) f |= F_SORT;
        topk[(size_t)b * PRE_NMS + r] = idx;
    }
    if (f) atomicOr(&flags[b], f);
    if (t == 0) skey[b] = s[PRE_NMS - 1];
}

// ------ independent top-k proof: #(comp > s[5999]) == 5999, #(>=) == 6000 ----
__global__ __launch_bounds__(256) void count_kernel(const float* __restrict__ obj,
                                                    const unsigned long long* __restrict__ skey,
                                                    unsigned* __restrict__ cgt,
                                                    unsigned* __restrict__ cge) {
    const int b = blockIdx.y;
    const unsigned long long C = skey[b];
    const float* p = obj + (size_t)b * NPB;
    unsigned gt = 0, ge = 0;
    const int stride = gridDim.x * 256;
    for (int i = blockIdx.x * 256 + threadIdx.x; i < NPB; i += stride) {
        unsigned long long comp = ((unsigned long long)monot(p[i]) << 32) | (unsigned)(~i);
        gt += comp > C ? 1u : 0u;
        ge += comp >= C ? 1u : 0u;
    }
    for (int o = 32; o; o >>= 1) { gt += __shfl_down(gt, o); ge += __shfl_down(ge, o); }
    if ((threadIdx.x & 63) == 0) { atomicAdd(&cgt[b], gt); atomicAdd(&cge[b], ge); }
}

// ---------------- Phase 2: decode + clip + valid ----------------
__global__ __launch_bounds__(256) void decode_kernel(const float* __restrict__ anchors,
                                                     const float* __restrict__ deltas,
                                                     const unsigned* __restrict__ topk,
                                                     const int* __restrict__ imh,
                                                     const int* __restrict__ imw,
                                                     float* __restrict__ boxes,
                                                     float* __restrict__ areas,
                                                     unsigned long long* __restrict__ validm) {
    const int b = blockIdx.y;
    const int r = blockIdx.x * 256 + threadIdx.x;
    const bool active = r < PRE_NMS;
    // defensive scalar read: int32 expected, tolerate float32 encoding
    int vh = imh[0], vw = imw[0];
    float ih = (vh > 0 && vh < (1 << 20)) ? (float)vh : __int_as_float(vh);
    float iw = (vw > 0 && vw < (1 << 20)) ? (float)vw : __int_as_float(vw);
    bool valid = false;
    if (active) {
        unsigned idx = topk[(size_t)b * PRE_NMS + r];
        if (idx >= NPB) idx = 0;   // canary will have fired; avoid OOB
        const float4 a = ((const float4*)anchors)[(size_t)b * NPB + idx];
        const float4 d = ((const float4*)deltas)[(size_t)b * NPB + idx];
        float wa = a.z - a.x, ha = a.w - a.y;
        float cxa = a.x + 0.5f * wa, cya = a.y + 0.5f * ha;  // 0.5*x exact: fma-safe
        float dw = fminf(d.z, BBOX_CLIP), dh = fminf(d.w, BBOX_CLIP);
        // reference op order: round(dx*wa) then add -> non-contractible mul
        float cx = __fadd_rn(__fmul_rn(d.x, wa), cxa);
        float cy = __fadd_rn(__fmul_rn(d.y, ha), cya);
        // correctly-rounded f32 exp via f64 (within numpy/XLA exp agreement band)
        float ew = (float)::exp((double)dw), eh = (float)::exp((double)dh);
        float w = __fmul_rn(ew, wa), h = __fmul_rn(eh, ha);
        float x1 = cx - 0.5f * w, y1 = cy - 0.5f * h;        // 0.5*x exact: fma-safe
        float x2 = cx + 0.5f * w, y2 = cy + 0.5f * h;
        x1 = fminf(fmaxf(x1, 0.f), iw); y1 = fminf(fmaxf(y1, 0.f), ih);
        x2 = fminf(fmaxf(x2, 0.f), iw); y2 = fminf(fmaxf(y2, 0.f), ih);
        valid = (x2 - x1 >= 1.0f) && (y2 - y1 >= 1.0f);
        ((float4*)boxes)[(size_t)b * PRE_NMS + r] = make_float4(x1, y1, x2, y2);
        areas[(size_t)b * PRE_NMS + r] = __fmul_rn(x2 - x1, y2 - y1);
    }
    unsigned long long bal = __ballot(valid);
    int w = r >> 6;
    if ((threadIdx.x & 63) == 0 && w < NWORDS) validm[(size_t)b * NWORDS + w] = bal;
}

// ------- Phase 3: suppression bitmask (j > i, IoU > 0.7), ALL words --------
__global__ __launch_bounds__(256) void mask_kernel(const float* __restrict__ boxes,
                                                   const float* __restrict__ areas,
                                                   unsigned long long* __restrict__ mask) {
    const int i = blockIdx.x, b = blockIdx.y;
    const float4 bi = ((const float4*)boxes)[(size_t)b * PRE_NMS + i];
    const float ai = areas[(size_t)b * PRE_NMS + i];
    unsigned long long* row = mask + ((size_t)b * PRE_NMS + i) * NWORDS;
    const int wv = threadIdx.x >> 6, ln = threadIdx.x & 63;
    for (int w = wv; w < NWORDS; w += 4) {
        int j = (w << 6) + ln;
        bool pred = false;
        if (j > i && j < PRE_NMS) {
            const float4 bj = ((const float4*)boxes)[(size_t)b * PRE_NMS + j];
            float xx1 = fmaxf(bi.x, bj.x), yy1 = fmaxf(bi.y, bj.y);
            float xx2 = fminf(bi.z, bj.z), yy2 = fminf(bi.w, bj.w);
            float inter = __fmul_rn(fmaxf(__fsub_rn(xx2, xx1), 0.f),
                                    fmaxf(__fsub_rn(yy2, yy1), 0.f));
            // reference order: ((ai + aj) - inter) + 1e-9
            float den = __fadd_rn(__fsub_rn(__fadd_rn(ai, areas[(size_t)b * PRE_NMS + j]),
                                            inter), 1e-9f);
            float iou = __fdiv_rn(inter, den);
            pred = iou > NMS_THR;
        }
        unsigned long long m = __ballot(pred);
        if (ln == 0) row[w] = m;
    }
}

// ------- Phase 4: serial greedy scan — simple LDS version, 1 wave/batch -----
__global__ __launch_bounds__(64) void scan_kernel(const unsigned long long* __restrict__ mask,
                                                  const unsigned long long* __restrict__ validm,
                                                  const float* __restrict__ boxes,
                                                  float* __restrict__ out) {
    __shared__ unsigned long long rem[128];   // words 0..93 live
    const int b = blockIdx.x, lane = threadIdx.x;
    const unsigned long long* mb = mask + (size_t)b * PRE_NMS * NWORDS;
    rem[lane] = ~validm[(size_t)b * NWORDS + lane];                  // words 0..63
    if (lane < NWORDS - 64)
        rem[64 + lane] = ~validm[(size_t)b * NWORDS + 64 + lane];    // words 64..93
    __syncthreads();
    int count = 0;
    for (int i = 0; i < PRE_NMS && count < POST_NMS; ++i) {
        const unsigned long long wv = rem[i >> 6];    // uniform read (broadcast)
        __syncthreads();                              // order read before any OR-write
        if (!((wv >> (i & 63)) & 1ULL)) {
            const unsigned long long* row = mb + (size_t)i * NWORDS;
            rem[lane] |= row[lane];
            if (lane < NWORDS - 64) rem[64 + lane] |= row[64 + lane];
            if (lane < 4)
                out[((size_t)b * POST_NMS + count) * 4 + lane] =
                    boxes[((size_t)b * PRE_NMS + i) * 4 + lane];
            ++count;
        }
        __syncthreads();                              // order OR-writes before next read
    }
}

// ------- Final: canary writer — encodes any invariant violation in absmax ---
__global__ __launch_bounds__(64) void finalize_kernel(const unsigned* __restrict__ flags,
                                                      const unsigned* __restrict__ cgt,
                                                      const unsigned* __restrict__ cge,
                                                      const unsigned* __restrict__ ccnt,
                                                      float* __restrict__ out) {
    int b = threadIdx.x;
    if (b >= NBATCH) return;
    float canary = 0.f;
    if (ccnt[b] > CANDCAP)       canary = 111000.f;  // compact overflow
    else if (ccnt[b] < PRE_NMS)  canary = 222000.f;  // threshold selected too few
    if (flags[b] & F_SORT)       canary = 333000.f;  // sorted list not strictly descending
    if (flags[b] & F_COMP)       canary = 444000.f;  // composite<->input mismatch
    if (flags[b] & F_OOB)        canary = 777000.f;  // index out of range
    if (cgt[b] != PRE_NMS - 1)   canary = 555000.f;  // #(comp > s[5999]) != 5999
    if (cge[b] != PRE_NMS)       canary = 666000.f;  // #(comp >= s[5999]) != 6000
    if (canary != 0.f) out[(size_t)b * POST_NMS * 4] = canary;
}

extern "C" void kernel_launch(void* const* d_in, const int* in_sizes, int n_in,
                              void* d_out, int out_size, void* d_ws, size_t ws_size,
                              hipStream_t stream) {
    const float* anchors = (const float*)d_in[0];
    const float* obj     = (const float*)d_in[1];
    const float* deltas  = (const float*)d_in[2];
    const int*   imh     = (const int*)d_in[3];
    const int*   imw     = (const int*)d_in[4];
    float* out = (float*)d_out;
    char* ws = (char*)d_ws;

    size_t off = 0;
    auto alloc = [&](size_t bytes) {
        size_t o = off;
        off = (off + bytes + 511) & ~(size_t)511;
        return o;
    };
    const size_t HIST  = alloc((size_t)NBATCH * NBINS * 4);
    const size_t TBIN  = alloc((size_t)NBATCH * 4);
    const size_t CCNT  = alloc((size_t)NBATCH * 4);
    const size_t CAND  = alloc((size_t)NBATCH * CANDCAP * 8);
    const size_t TOPK  = alloc((size_t)NBATCH * PRE_NMS * 4);
    const size_t BOX   = alloc((size_t)NBATCH * PRE_NMS * 16);
    const size_t AREA  = alloc((size_t)NBATCH * PRE_NMS * 4);
    const size_t VALID = alloc((size_t)NBATCH * NWORDS * 8);
    const size_t SKEY  = alloc((size_t)NBATCH * 8);
    const size_t FLAGS = alloc((size_t)NBATCH * 4);
    const size_t CGT   = alloc((size_t)NBATCH * 4);
    const size_t CGE   = alloc((size_t)NBATCH * 4);
    const size_t MASK  = alloc((size_t)NBATCH * PRE_NMS * NWORDS * 8);
    if (ws_size < off) return;  // visible failure: output left as harness zeros

    unsigned*            hist   = (unsigned*)(ws + HIST);
    unsigned*            tbin   = (unsigned*)(ws + TBIN);
    unsigned*            ccnt   = (unsigned*)(ws + CCNT);
    unsigned long long*  cand   = (unsigned long long*)(ws + CAND);
    unsigned*            topk   = (unsigned*)(ws + TOPK);
    float*               boxes  = (float*)(ws + BOX);
    float*               areas  = (float*)(ws + AREA);
    unsigned long long*  validm = (unsigned long long*)(ws + VALID);
    unsigned long long*  skey   = (unsigned long long*)(ws + SKEY);
    unsigned*            flags  = (unsigned*)(ws + FLAGS);
    unsigned*            cgt    = (unsigned*)(ws + CGT);
    unsigned*            cge    = (unsigned*)(ws + CGE);
    unsigned long long*  maskp  = (unsigned long long*)(ws + MASK);

    hipMemsetAsync(hist, 0, (size_t)NBATCH * NBINS * 4, stream);
    hipMemsetAsync(ccnt, 0, (size_t)NBATCH * 4, stream);
    hipMemsetAsync(cand, 0, (size_t)NBATCH * CANDCAP * 8, stream);   // 0 = -inf sentinel
    hipMemsetAsync(flags, 0, (size_t)NBATCH * 4, stream);
    hipMemsetAsync(cgt,   0, (size_t)NBATCH * 4, stream);
    hipMemsetAsync(cge,   0, (size_t)NBATCH * 4, stream);
    hipMemsetAsync(out, 0, (size_t)out_size * sizeof(float), stream);

    hist_kernel   <<<dim3(128, NBATCH), 256, 0, stream>>>(obj, hist);
    thresh_kernel <<<dim3(NBATCH), 256, 0, stream>>>(hist, tbin);
    compact_kernel<<<dim3(128, NBATCH), 256, 0, stream>>>(obj, tbin, cand, ccnt);
    sort_kernel   <<<dim3(NBATCH), 1024, 0, stream>>>(cand, obj, topk, skey, flags);
    count_kernel  <<<dim3(64, NBATCH), 256, 0, stream>>>(obj, skey, cgt, cge);
    decode_kernel <<<dim3((PRE_NMS + 255) / 256, NBATCH), 256, 0, stream>>>(
        anchors, deltas, topk, imh, imw, boxes, areas, validm);
    mask_kernel   <<<dim3(PRE_NMS, NBATCH), 256, 0, stream>>>(boxes, areas, maskp);
    scan_kernel   <<<dim3(NBATCH), 64, 0, stream>>>(maskp, validm, boxes, out);
    finalize_kernel<<<1, 64, 0, stream>>>(flags, cgt, cge, ccnt, out);
    (void)in_sizes; (void)n_in; (void)ws_size;
}

// Round 4
// 1422.894 us; speedup vs baseline: 1.0538x; 1.0538x over previous
//
#include <hip/hip_runtime.h>
#include <cstdint>
#include <cmath>

#define NBATCH   8
#define NPB      500000
#define PRE_NMS  6000
#define POST_NMS 1000
#define NWORDS   94          // ceil(6000/64)
#define NBINS    16384       // 14-bit float prefix (sign+exp+5 mantissa)
#define CANDCAP  8192        // candidate cap per batch (expected ~6800 worst case)
#define BBOX_CLIP 4.135166556742356f   // log(1000/16)
#define NMS_THR  0.7f
#define TI 8                 // mask rows per block
#define TJ 512               // mask j-tile staged in LDS

#define F_SORT 1u
#define F_COMP 2u
#define F_OOB  4u

// monotone map: ascending uint <=> ascending float
__device__ __forceinline__ unsigned monot(float f) {
    unsigned b = __float_as_uint(f);
    return (b & 0x80000000u) ? ~b : (b | 0x80000000u);
}

// ---------------- Phase 1a: 16384-bin histogram of key prefix ----------------
__global__ __launch_bounds__(256) void hist_kernel(const float* __restrict__ obj,
                                                   unsigned* __restrict__ hist) {
    __shared__ unsigned lh[NBINS];   // 64 KiB
    const int b = blockIdx.y;
    for (int q = threadIdx.x; q < NBINS; q += 256) lh[q] = 0;
    __syncthreads();
    const float* p = obj + (size_t)b * NPB;
    const int stride = gridDim.x * 256;
    for (int i = blockIdx.x * 256 + threadIdx.x; i < NPB; i += stride) {
        unsigned u = monot(p[i]);
        atomicAdd(&lh[u >> 18], 1u);
    }
    __syncthreads();
    unsigned* gh = hist + (size_t)b * NBINS;
    for (int q = threadIdx.x; q < NBINS; q += 256) {
        unsigned v = lh[q];
        if (v) atomicAdd(&gh[q], v);
    }
}

// ------- Phase 1b: find threshold bin (descending cumulative >= 6000) -------
__global__ __launch_bounds__(256) void thresh_kernel(const unsigned* __restrict__ hist,
                                                     unsigned* __restrict__ tbin) {
    __shared__ unsigned part[256], pre[256];
    const int b = blockIdx.x;
    const unsigned* gh = hist + (size_t)b * NBINS;
    const int t = threadIdx.x;
    const int PER = NBINS / 256;     // 64 bins per thread
    unsigned s = 0;
    for (int d = 0; d < PER; ++d) s += gh[NBINS - 1 - (t * PER + d)];
    part[t] = s;
    __syncthreads();
    if (t == 0) {
        unsigned run = 0;
        for (int q = 0; q < 256; ++q) { pre[q] = run; run += part[q]; }
    }
    __syncthreads();
    unsigned c = pre[t];
    if (c < PRE_NMS && c + part[t] >= PRE_NMS) {
        unsigned run = c;
        for (int d = 0; d < PER; ++d) {
            int bin = NBINS - 1 - (t * PER + d);
            run += gh[bin];
            if (run >= PRE_NMS) { tbin[b] = (unsigned)bin; break; }
        }
    }
}

// ---------------- Phase 1c: compact candidates (key,idx) ----------------
__global__ __launch_bounds__(256) void compact_kernel(const float* __restrict__ obj,
                                                      const unsigned* __restrict__ tbin,
                                                      unsigned long long* __restrict__ cand,
                                                      unsigned* __restrict__ ccnt) {
    const int b = blockIdx.y;
    const unsigned T = tbin[b];
    const float* p = obj + (size_t)b * NPB;
    unsigned long long* cb = cand + (size_t)b * CANDCAP;
    const int stride = gridDim.x * 256;
    for (int i = blockIdx.x * 256 + threadIdx.x; i < NPB; i += stride) {
        unsigned u = monot(p[i]);
        if ((u >> 18) >= T) {
            unsigned pos = atomicAdd(&ccnt[b], 1u);
            if (pos < CANDCAP)  // composite: value desc, then index asc (via ~i)
                cb[pos] = ((unsigned long long)u << 32) | (unsigned)(~i);
        }
    }
}

// -------- Phase 1d: per-batch bitonic sort (descending) in 64 KiB LDS -------
// + self-verification: strict descending, composite<->input consistency.
__global__ __launch_bounds__(1024) void sort_kernel(const unsigned long long* __restrict__ cand,
                                                    const float* __restrict__ obj,
                                                    unsigned* __restrict__ topk,
                                                    unsigned long long* __restrict__ skey,
                                                    unsigned* __restrict__ flags) {
    __shared__ unsigned long long s[CANDCAP];  // 64 KiB
    const int b = blockIdx.x, t = threadIdx.x;
    const unsigned long long* cb = cand + (size_t)b * CANDCAP;
    for (int i = t; i < CANDCAP; i += 1024) s[i] = cb[i];
    __syncthreads();
    for (unsigned k = 2; k <= CANDCAP; k <<= 1) {
        for (unsigned j = k >> 1; j > 0; j >>= 1) {
            for (unsigned ii = t; ii < CANDCAP; ii += 1024) {
                unsigned l = ii ^ j;
                if (l > ii) {
                    unsigned long long a = s[ii], c = s[l];
                    bool up = (ii & k) == 0;
                    if (up ? (a < c) : (a > c)) { s[ii] = c; s[l] = a; }
                }
            }
            __syncthreads();
        }
    }
    // ---- checks + emit ----
    unsigned f = 0;
    for (int r = t; r < PRE_NMS; r += 1024) {
        unsigned long long c = s[r];
        unsigned idx = ~(unsigned)(c & 0xffffffffULL);
        if (idx >= NPB) { f |= F_OOB; idx = 0; }
        else if (monot(obj[(size_t)b * NPB + idx]) != (unsigned)(c >> 32)) f |= F_COMP;
        if (r < PRE_NMS - 1 && !(c > s[r + 1])) f |= F_SORT;
        topk[(size_t)b * PRE_NMS + r] = idx;
    }
    if (f) atomicOr(&flags[b], f);
    if (t == 0) skey[b] = s[PRE_NMS - 1];
}

// ------ independent top-k proof: #(comp > s[5999]) == 5999, #(>=) == 6000 ----
__global__ __launch_bounds__(256) void count_kernel(const float* __restrict__ obj,
                                                    const unsigned long long* __restrict__ skey,
                                                    unsigned* __restrict__ cgt,
                                                    unsigned* __restrict__ cge) {
    const int b = blockIdx.y;
    const unsigned long long C = skey[b];
    const float* p = obj + (size_t)b * NPB;
    unsigned gt = 0, ge = 0;
    const int stride = gridDim.x * 256;
    for (int i = blockIdx.x * 256 + threadIdx.x; i < NPB; i += stride) {
        unsigned long long comp = ((unsigned long long)monot(p[i]) << 32) | (unsigned)(~i);
        gt += comp > C ? 1u : 0u;
        ge += comp >= C ? 1u : 0u;
    }
    for (int o = 32; o; o >>= 1) { gt += __shfl_down(gt, o); ge += __shfl_down(ge, o); }
    if ((threadIdx.x & 63) == 0) { atomicAdd(&cgt[b], gt); atomicAdd(&cge[b], ge); }
}

// ---------------- Phase 2: decode + clip + valid (numerics FROZEN) ----------
__global__ __launch_bounds__(256) void decode_kernel(const float* __restrict__ anchors,
                                                     const float* __restrict__ deltas,
                                                     const unsigned* __restrict__ topk,
                                                     const int* __restrict__ imh,
                                                     const int* __restrict__ imw,
                                                     float* __restrict__ boxes,
                                                     float* __restrict__ areas,
                                                     unsigned long long* __restrict__ validm) {
    const int b = blockIdx.y;
    const int r = blockIdx.x * 256 + threadIdx.x;
    const bool active = r < PRE_NMS;
    int vh = imh[0], vw = imw[0];
    float ih = (vh > 0 && vh < (1 << 20)) ? (float)vh : __int_as_float(vh);
    float iw = (vw > 0 && vw < (1 << 20)) ? (float)vw : __int_as_float(vw);
    bool valid = false;
    if (active) {
        unsigned idx = topk[(size_t)b * PRE_NMS + r];
        if (idx >= NPB) idx = 0;   // canary will have fired; avoid OOB
        const float4 a = ((const float4*)anchors)[(size_t)b * NPB + idx];
        const float4 d = ((const float4*)deltas)[(size_t)b * NPB + idx];
        float wa = a.z - a.x, ha = a.w - a.y;
        float cxa = a.x + 0.5f * wa, cya = a.y + 0.5f * ha;  // 0.5*x exact: fma-safe
        float dw = fminf(d.z, BBOX_CLIP), dh = fminf(d.w, BBOX_CLIP);
        float cx = __fadd_rn(__fmul_rn(d.x, wa), cxa);
        float cy = __fadd_rn(__fmul_rn(d.y, ha), cya);
        float ew = (float)::exp((double)dw), eh = (float)::exp((double)dh);
        float w = __fmul_rn(ew, wa), h = __fmul_rn(eh, ha);
        float x1 = cx - 0.5f * w, y1 = cy - 0.5f * h;
        float x2 = cx + 0.5f * w, y2 = cy + 0.5f * h;
        x1 = fminf(fmaxf(x1, 0.f), iw); y1 = fminf(fmaxf(y1, 0.f), ih);
        x2 = fminf(fmaxf(x2, 0.f), iw); y2 = fminf(fmaxf(y2, 0.f), ih);
        valid = (x2 - x1 >= 1.0f) && (y2 - y1 >= 1.0f);
        ((float4*)boxes)[(size_t)b * PRE_NMS + r] = make_float4(x1, y1, x2, y2);
        areas[(size_t)b * PRE_NMS + r] = __fmul_rn(x2 - x1, y2 - y1);
    }
    unsigned long long bal = __ballot(valid);
    int w = r >> 6;
    if ((threadIdx.x & 63) == 0 && w < NWORDS) validm[(size_t)b * NWORDS + w] = bal;
}

// ------- Phase 3: suppression bitmask, UPPER-TRIANGLE words only -----------
// 8 rows/block (2 per wave), j staged in LDS tiles, XCD-pinned (b = bid & 7)
// so batch b's mask rows land in XCD b's L2 for scan_kernel (also block b).
__global__ __launch_bounds__(256) void mask_kernel(const float* __restrict__ boxes,
                                                   const float* __restrict__ areas,
                                                   unsigned long long* __restrict__ mask) {
    __shared__ float4 sb[TJ];
    __shared__ float  sa[TJ];
    const int b = blockIdx.x & 7;            // XCD pin: block -> XCD round-robin
    const int i0 = (blockIdx.x >> 3) * TI;
    const int jbase = (i0 >> 6) << 6;
    const int wv = threadIdx.x >> 6, ln = threadIdx.x & 63;
    const int ia = i0 + 2 * wv, ic = ia + 1;  // 2 rows per wave; 6000 % 8 == 0
    const float4 bA = ((const float4*)boxes)[(size_t)b * PRE_NMS + ia];
    const float4 bC = ((const float4*)boxes)[(size_t)b * PRE_NMS + ic];
    const float aA = areas[(size_t)b * PRE_NMS + ia];
    const float aC = areas[(size_t)b * PRE_NMS + ic];
    unsigned long long* rowA = mask + ((size_t)b * PRE_NMS + ia) * NWORDS;
    unsigned long long* rowC = mask + ((size_t)b * PRE_NMS + ic) * NWORDS;
    const int wA = ia >> 6, wC = ic >> 6;
    for (int t0 = jbase; t0 < NWORDS * 64; t0 += TJ) {
        for (int e = threadIdx.x; e < TJ; e += 256) {
            int j = t0 + e;
            if (j < PRE_NMS) {
                sb[e] = ((const float4*)boxes)[(size_t)b * PRE_NMS + j];
                sa[e] = areas[(size_t)b * PRE_NMS + j];
            } else { sb[e] = make_float4(0.f, 0.f, 0.f, 0.f); sa[e] = 0.f; }
        }
        __syncthreads();
        for (int wl = 0; wl < TJ / 64; ++wl) {
            const int w = (t0 >> 6) + wl;
            if (w >= NWORDS) break;
            const int e = wl * 64 + ln;
            const int j = t0 + e;
            const float4 bj = sb[e];
            const float aj = sa[e];
            bool pA = false, pC = false;
            if (j < PRE_NMS) {   // EXACT same fp sequence as the passing round-3 kernel
                float xx1 = fmaxf(bA.x, bj.x), yy1 = fmaxf(bA.y, bj.y);
                float xx2 = fminf(bA.z, bj.z), yy2 = fminf(bA.w, bj.w);
                float inter = __fmul_rn(fmaxf(__fsub_rn(xx2, xx1), 0.f),
                                        fmaxf(__fsub_rn(yy2, yy1), 0.f));
                float den = __fadd_rn(__fsub_rn(__fadd_rn(aA, aj), inter), 1e-9f);
                pA = (j > ia) && (__fdiv_rn(inter, den) > NMS_THR);
                xx1 = fmaxf(bC.x, bj.x); yy1 = fmaxf(bC.y, bj.y);
                xx2 = fminf(bC.z, bj.z); yy2 = fminf(bC.w, bj.w);
                inter = __fmul_rn(fmaxf(__fsub_rn(xx2, xx1), 0.f),
                                  fmaxf(__fsub_rn(yy2, yy1), 0.f));
                den = __fadd_rn(__fsub_rn(__fadd_rn(aC, aj), inter), 1e-9f);
                pC = (j > ic) && (__fdiv_rn(inter, den) > NMS_THR);
            }
            unsigned long long mA = __ballot(pA), mC = __ballot(pC);
            if (ln == 0) {
                if (w >= wA) rowA[w] = mA;   // only own-diagonal-and-above words
                if (w >= wC) rowC[w] = mC;
            }
        }
        __syncthreads();
    }
}

// ------- Phase 4: serial greedy scan — register rem + ctz skip-to-keep ------
// lane l owns rem words l (r0) and 64+l (r1, l<30). Per keep: ffz + wave-min
// (6 shfl_xor) finds the next keep directly; suppressed positions cost nothing.
// mask rows only valid for words >= k>>6 (upper-triangle storage) -> masked OR.
__global__ __launch_bounds__(64) void scan_kernel(const unsigned long long* __restrict__ mask,
                                                  const unsigned long long* __restrict__ validm,
                                                  const float* __restrict__ boxes,
                                                  float* __restrict__ out) {
    const int b = blockIdx.x, lane = threadIdx.x;
    const unsigned long long* mb = mask + (size_t)b * PRE_NMS * NWORDS;
    unsigned long long r0 = ~validm[(size_t)b * NWORDS + lane];
    unsigned long long r1 = (lane < NWORDS - 64) ? ~validm[(size_t)b * NWORDS + 64 + lane]
                                                 : ~0ULL;
    const int w2 = 64 + lane;
    int p = 0, count = 0;
    while (count < POST_NMS) {
        // first zero bit at position >= p (bits < p forced to 1)
        const int pw = p >> 6, pb = p & 63;
        unsigned long long x = r0, y = r1;
        if (lane < pw) x = ~0ULL;
        else if (lane == pw) x |= ((1ULL << pb) - 1ULL);
        if (w2 == pw) y |= ((1ULL << pb) - 1ULL);      // w2 < pw impossible for pw<=93... guard anyway
        const unsigned long long nx = ~x, ny = ~y;
        int c0 = nx ? (lane * 64 + (int)__builtin_ctzll(nx)) : (1 << 30);
        int c1 = ny ? (w2 * 64 + (int)__builtin_ctzll(ny)) : (1 << 30);
        int c = c0 < c1 ? c0 : c1;
#pragma unroll
        for (int o = 32; o; o >>= 1) {
            int other = __shfl_xor(c, o);
            c = other < c ? other : c;
        }
        if (c >= PRE_NMS) break;
        const int k = c, kw = k >> 6;
        const unsigned long long* row = mb + (size_t)k * NWORDS;
        unsigned long long m0 = row[lane];
        unsigned long long m1 = (lane < NWORDS - 64) ? row[w2] : 0ULL;
        if (lane < kw) m0 = 0ULL;                 // below-diagonal words are unwritten
        if (w2 < kw) m1 = 0ULL;
        if (lane == 0)
            ((float4*)out)[(size_t)b * POST_NMS + count] =
                ((const float4*)boxes)[(size_t)b * PRE_NMS + k];
        r0 |= m0; r1 |= m1;
        ++count;
        p = k + 1;
    }
}

// ------- Final: canary writer — encodes any invariant violation in absmax ---
__global__ __launch_bounds__(64) void finalize_kernel(const unsigned* __restrict__ flags,
                                                      const unsigned* __restrict__ cgt,
                                                      const unsigned* __restrict__ cge,
                                                      const unsigned* __restrict__ ccnt,
                                                      float* __restrict__ out) {
    int b = threadIdx.x;
    if (b >= NBATCH) return;
    float canary = 0.f;
    if (ccnt[b] > CANDCAP)       canary = 111000.f;
    else if (ccnt[b] < PRE_NMS)  canary = 222000.f;
    if (flags[b] & F_SORT)       canary = 333000.f;
    if (flags[b] & F_COMP)       canary = 444000.f;
    if (flags[b] & F_OOB)        canary = 777000.f;
    if (cgt[b] != PRE_NMS - 1)   canary = 555000.f;
    if (cge[b] != PRE_NMS)       canary = 666000.f;
    if (canary != 0.f) out[(size_t)b * POST_NMS * 4] = canary;
}

extern "C" void kernel_launch(void* const* d_in, const int* in_sizes, int n_in,
                              void* d_out, int out_size, void* d_ws, size_t ws_size,
                              hipStream_t stream) {
    const float* anchors = (const float*)d_in[0];
    const float* obj     = (const float*)d_in[1];
    const float* deltas  = (const float*)d_in[2];
    const int*   imh     = (const int*)d_in[3];
    const int*   imw     = (const int*)d_in[4];
    float* out = (float*)d_out;
    char* ws = (char*)d_ws;

    size_t off = 0;
    auto alloc = [&](size_t bytes) {
        size_t o = off;
        off = (off + bytes + 511) & ~(size_t)511;
        return o;
    };
    const size_t HIST  = alloc((size_t)NBATCH * NBINS * 4);
    const size_t TBIN  = alloc((size_t)NBATCH * 4);
    const size_t CCNT  = alloc((size_t)NBATCH * 4);
    const size_t CAND  = alloc((size_t)NBATCH * CANDCAP * 8);
    const size_t TOPK  = alloc((size_t)NBATCH * PRE_NMS * 4);
    const size_t BOX   = alloc((size_t)NBATCH * PRE_NMS * 16);
    const size_t AREA  = alloc((size_t)NBATCH * PRE_NMS * 4);
    const size_t VALID = alloc((size_t)NBATCH * NWORDS * 8);
    const size_t SKEY  = alloc((size_t)NBATCH * 8);
    const size_t FLAGS = alloc((size_t)NBATCH * 4);
    const size_t CGT   = alloc((size_t)NBATCH * 4);
    const size_t CGE   = alloc((size_t)NBATCH * 4);
    const size_t MASK  = alloc((size_t)NBATCH * PRE_NMS * NWORDS * 8);
    if (ws_size < off) return;

    unsigned*            hist   = (unsigned*)(ws + HIST);
    unsigned*            tbin   = (unsigned*)(ws + TBIN);
    unsigned*            ccnt   = (unsigned*)(ws + CCNT);
    unsigned long long*  cand   = (unsigned long long*)(ws + CAND);
    unsigned*            topk   = (unsigned*)(ws + TOPK);
    float*               boxes  = (float*)(ws + BOX);
    float*               areas  = (float*)(ws + AREA);
    unsigned long long*  validm = (unsigned long long*)(ws + VALID);
    unsigned long long*  skey   = (unsigned long long*)(ws + SKEY);
    unsigned*            flags  = (unsigned*)(ws + FLAGS);
    unsigned*            cgt    = (unsigned*)(ws + CGT);
    unsigned*            cge    = (unsigned*)(ws + CGE);
    unsigned long long*  maskp  = (unsigned long long*)(ws + MASK);

    hipMemsetAsync(hist, 0, (size_t)NBATCH * NBINS * 4, stream);
    hipMemsetAsync(ccnt, 0, (size_t)NBATCH * 4, stream);
    hipMemsetAsync(cand, 0, (size_t)NBATCH * CANDCAP * 8, stream);   // 0 = -inf sentinel
    hipMemsetAsync(flags, 0, (size_t)NBATCH * 4, stream);
    hipMemsetAsync(cgt,   0, (size_t)NBATCH * 4, stream);
    hipMemsetAsync(cge,   0, (size_t)NBATCH * 4, stream);
    hipMemsetAsync(out, 0, (size_t)out_size * sizeof(float), stream);

    hist_kernel   <<<dim3(128, NBATCH), 256, 0, stream>>>(obj, hist);
    thresh_kernel <<<dim3(NBATCH), 256, 0, stream>>>(hist, tbin);
    compact_kernel<<<dim3(128, NBATCH), 256, 0, stream>>>(obj, tbin, cand, ccnt);
    sort_kernel   <<<dim3(NBATCH), 1024, 0, stream>>>(cand, obj, topk, skey, flags);
    count_kernel  <<<dim3(64, NBATCH), 256, 0, stream>>>(obj, skey, cgt, cge);
    decode_kernel <<<dim3((PRE_NMS + 255) / 256, NBATCH), 256, 0, stream>>>(
        anchors, deltas, topk, imh, imw, boxes, areas, validm);
    mask_kernel   <<<dim3((PRE_NMS / TI) * NBATCH), 256, 0, stream>>>(boxes, areas, maskp);
    scan_kernel   <<<dim3(NBATCH), 64, 0, stream>>>(maskp, validm, boxes, out);
    finalize_kernel<<<1, 64, 0, stream>>>(flags, cgt, cge, ccnt, out);
    (void)in_sizes; (void)n_in; (void)ws_size;
}

// Round 5
// 885.841 us; speedup vs baseline: 1.6927x; 1.6063x over previous
//
#include <hip/hip_runtime.h>
#include <cstdint>
#include <cmath>

#define NBATCH   8
#define NPB      500000
#define PRE_NMS  6000
#define POST_NMS 1000
#define NWORDS   94          // ceil(6000/64)
#define NBINS    16384       // 14-bit float prefix (sign+exp+5 mantissa)
#define CANDCAP  8192        // candidate cap per batch (expected ~6800 worst case)
#define BBOX_CLIP 4.135166556742356f   // log(1000/16)
#define NMS_THR  0.7f
#define TI 8                 // mask rows per block
#define TJ 512               // mask j-tile staged in LDS
#define WIN 16               // scan window (64 % WIN == 0: window never straddles words)

#define F_SORT 1u
#define F_COMP 2u
#define F_OOB  4u

// monotone map: ascending uint <=> ascending float
__device__ __forceinline__ unsigned monot(float f) {
    unsigned b = __float_as_uint(f);
    return (b & 0x80000000u) ? ~b : (b | 0x80000000u);
}

// ---------------- Phase 1a: 16384-bin histogram of key prefix ----------------
__global__ __launch_bounds__(256) void hist_kernel(const float* __restrict__ obj,
                                                   unsigned* __restrict__ hist) {
    __shared__ unsigned lh[NBINS];   // 64 KiB
    const int b = blockIdx.y;
    for (int q = threadIdx.x; q < NBINS; q += 256) lh[q] = 0;
    __syncthreads();
    const float* p = obj + (size_t)b * NPB;
    const int stride = gridDim.x * 256;
    for (int i = blockIdx.x * 256 + threadIdx.x; i < NPB; i += stride) {
        unsigned u = monot(p[i]);
        atomicAdd(&lh[u >> 18], 1u);
    }
    __syncthreads();
    unsigned* gh = hist + (size_t)b * NBINS;
    for (int q = threadIdx.x; q < NBINS; q += 256) {
        unsigned v = lh[q];
        if (v) atomicAdd(&gh[q], v);
    }
}

// ------- Phase 1b: find threshold bin (descending cumulative >= 6000) -------
__global__ __launch_bounds__(256) void thresh_kernel(const unsigned* __restrict__ hist,
                                                     unsigned* __restrict__ tbin) {
    __shared__ unsigned part[256], pre[256];
    const int b = blockIdx.x;
    const unsigned* gh = hist + (size_t)b * NBINS;
    const int t = threadIdx.x;
    const int PER = NBINS / 256;     // 64 bins per thread
    unsigned s = 0;
    for (int d = 0; d < PER; ++d) s += gh[NBINS - 1 - (t * PER + d)];
    part[t] = s;
    __syncthreads();
    if (t == 0) {
        unsigned run = 0;
        for (int q = 0; q < 256; ++q) { pre[q] = run; run += part[q]; }
    }
    __syncthreads();
    unsigned c = pre[t];
    if (c < PRE_NMS && c + part[t] >= PRE_NMS) {
        unsigned run = c;
        for (int d = 0; d < PER; ++d) {
            int bin = NBINS - 1 - (t * PER + d);
            run += gh[bin];
            if (run >= PRE_NMS) { tbin[b] = (unsigned)bin; break; }
        }
    }
}

// ---------------- Phase 1c: compact candidates (key,idx) ----------------
__global__ __launch_bounds__(256) void compact_kernel(const float* __restrict__ obj,
                                                      const unsigned* __restrict__ tbin,
                                                      unsigned long long* __restrict__ cand,
                                                      unsigned* __restrict__ ccnt) {
    const int b = blockIdx.y;
    const unsigned T = tbin[b];
    const float* p = obj + (size_t)b * NPB;
    unsigned long long* cb = cand + (size_t)b * CANDCAP;
    const int stride = gridDim.x * 256;
    for (int i = blockIdx.x * 256 + threadIdx.x; i < NPB; i += stride) {
        unsigned u = monot(p[i]);
        if ((u >> 18) >= T) {
            unsigned pos = atomicAdd(&ccnt[b], 1u);
            if (pos < CANDCAP)  // composite: value desc, then index asc (via ~i)
                cb[pos] = ((unsigned long long)u << 32) | (unsigned)(~i);
        }
    }
}

// -------- Phase 1d: per-batch bitonic sort (descending) in 64 KiB LDS -------
// + self-verification: strict descending, composite<->input consistency.
__global__ __launch_bounds__(1024) void sort_kernel(const unsigned long long* __restrict__ cand,
                                                    const float* __restrict__ obj,
                                                    unsigned* __restrict__ topk,
                                                    unsigned long long* __restrict__ skey,
                                                    unsigned* __restrict__ flags) {
    __shared__ unsigned long long s[CANDCAP];  // 64 KiB
    const int b = blockIdx.x, t = threadIdx.x;
    const unsigned long long* cb = cand + (size_t)b * CANDCAP;
    for (int i = t; i < CANDCAP; i += 1024) s[i] = cb[i];
    __syncthreads();
    for (unsigned k = 2; k <= CANDCAP; k <<= 1) {
        for (unsigned j = k >> 1; j > 0; j >>= 1) {
            for (unsigned ii = t; ii < CANDCAP; ii += 1024) {
                unsigned l = ii ^ j;
                if (l > ii) {
                    unsigned long long a = s[ii], c = s[l];
                    bool up = (ii & k) == 0;
                    if (up ? (a < c) : (a > c)) { s[ii] = c; s[l] = a; }
                }
            }
            __syncthreads();
        }
    }
    // ---- checks + emit ----
    unsigned f = 0;
    for (int r = t; r < PRE_NMS; r += 1024) {
        unsigned long long c = s[r];
        unsigned idx = ~(unsigned)(c & 0xffffffffULL);
        if (idx >= NPB) { f |= F_OOB; idx = 0; }
        else if (monot(obj[(size_t)b * NPB + idx]) != (unsigned)(c >> 32)) f |= F_COMP;
        if (r < PRE_NMS - 1 && !(c > s[r + 1])) f |= F_SORT;
        topk[(size_t)b * PRE_NMS + r] = idx;
    }
    if (f) atomicOr(&flags[b], f);
    if (t == 0) skey[b] = s[PRE_NMS - 1];
}

// ------ independent top-k proof: #(comp > s[5999]) == 5999, #(>=) == 6000 ----
__global__ __launch_bounds__(256) void count_kernel(const float* __restrict__ obj,
                                                    const unsigned long long* __restrict__ skey,
                                                    unsigned* __restrict__ cgt,
                                                    unsigned* __restrict__ cge) {
    const int b = blockIdx.y;
    const unsigned long long C = skey[b];
    const float* p = obj + (size_t)b * NPB;
    unsigned gt = 0, ge = 0;
    const int stride = gridDim.x * 256;
    for (int i = blockIdx.x * 256 + threadIdx.x; i < NPB; i += stride) {
        unsigned long long comp = ((unsigned long long)monot(p[i]) << 32) | (unsigned)(~i);
        gt += comp > C ? 1u : 0u;
        ge += comp >= C ? 1u : 0u;
    }
    for (int o = 32; o; o >>= 1) { gt += __shfl_down(gt, o); ge += __shfl_down(ge, o); }
    if ((threadIdx.x & 63) == 0) { atomicAdd(&cgt[b], gt); atomicAdd(&cge[b], ge); }
}

// ---------------- Phase 2: decode + clip + valid (numerics FROZEN) ----------
__global__ __launch_bounds__(256) void decode_kernel(const float* __restrict__ anchors,
                                                     const float* __restrict__ deltas,
                                                     const unsigned* __restrict__ topk,
                                                     const int* __restrict__ imh,
                                                     const int* __restrict__ imw,
                                                     float* __restrict__ boxes,
                                                     float* __restrict__ areas,
                                                     unsigned long long* __restrict__ validm) {
    const int b = blockIdx.y;
    const int r = blockIdx.x * 256 + threadIdx.x;
    const bool active = r < PRE_NMS;
    int vh = imh[0], vw = imw[0];
    float ih = (vh > 0 && vh < (1 << 20)) ? (float)vh : __int_as_float(vh);
    float iw = (vw > 0 && vw < (1 << 20)) ? (float)vw : __int_as_float(vw);
    bool valid = false;
    if (active) {
        unsigned idx = topk[(size_t)b * PRE_NMS + r];
        if (idx >= NPB) idx = 0;   // canary will have fired; avoid OOB
        const float4 a = ((const float4*)anchors)[(size_t)b * NPB + idx];
        const float4 d = ((const float4*)deltas)[(size_t)b * NPB + idx];
        float wa = a.z - a.x, ha = a.w - a.y;
        float cxa = a.x + 0.5f * wa, cya = a.y + 0.5f * ha;  // 0.5*x exact: fma-safe
        float dw = fminf(d.z, BBOX_CLIP), dh = fminf(d.w, BBOX_CLIP);
        float cx = __fadd_rn(__fmul_rn(d.x, wa), cxa);
        float cy = __fadd_rn(__fmul_rn(d.y, ha), cya);
        float ew = (float)::exp((double)dw), eh = (float)::exp((double)dh);
        float w = __fmul_rn(ew, wa), h = __fmul_rn(eh, ha);
        float x1 = cx - 0.5f * w, y1 = cy - 0.5f * h;
        float x2 = cx + 0.5f * w, y2 = cy + 0.5f * h;
        x1 = fminf(fmaxf(x1, 0.f), iw); y1 = fminf(fmaxf(y1, 0.f), ih);
        x2 = fminf(fmaxf(x2, 0.f), iw); y2 = fminf(fmaxf(y2, 0.f), ih);
        valid = (x2 - x1 >= 1.0f) && (y2 - y1 >= 1.0f);
        ((float4*)boxes)[(size_t)b * PRE_NMS + r] = make_float4(x1, y1, x2, y2);
        areas[(size_t)b * PRE_NMS + r] = __fmul_rn(x2 - x1, y2 - y1);
    }
    unsigned long long bal = __ballot(valid);
    int w = r >> 6;
    if ((threadIdx.x & 63) == 0 && w < NWORDS) validm[(size_t)b * NWORDS + w] = bal;
}

// ------- Phase 3: suppression bitmask, UPPER-TRIANGLE words only -----------
__global__ __launch_bounds__(256) void mask_kernel(const float* __restrict__ boxes,
                                                   const float* __restrict__ areas,
                                                   unsigned long long* __restrict__ mask) {
    __shared__ float4 sb[TJ];
    __shared__ float  sa[TJ];
    const int b = blockIdx.x & 7;            // XCD pin: block -> XCD round-robin
    const int i0 = (blockIdx.x >> 3) * TI;
    const int jbase = (i0 >> 6) << 6;
    const int wv = threadIdx.x >> 6, ln = threadIdx.x & 63;
    const int ia = i0 + 2 * wv, ic = ia + 1;  // 2 rows per wave; 6000 % 8 == 0
    const float4 bA = ((const float4*)boxes)[(size_t)b * PRE_NMS + ia];
    const float4 bC = ((const float4*)boxes)[(size_t)b * PRE_NMS + ic];
    const float aA = areas[(size_t)b * PRE_NMS + ia];
    const float aC = areas[(size_t)b * PRE_NMS + ic];
    unsigned long long* rowA = mask + ((size_t)b * PRE_NMS + ia) * NWORDS;
    unsigned long long* rowC = mask + ((size_t)b * PRE_NMS + ic) * NWORDS;
    const int wA = ia >> 6, wC = ic >> 6;
    for (int t0 = jbase; t0 < NWORDS * 64; t0 += TJ) {
        for (int e = threadIdx.x; e < TJ; e += 256) {
            int j = t0 + e;
            if (j < PRE_NMS) {
                sb[e] = ((const float4*)boxes)[(size_t)b * PRE_NMS + j];
                sa[e] = areas[(size_t)b * PRE_NMS + j];
            } else { sb[e] = make_float4(0.f, 0.f, 0.f, 0.f); sa[e] = 0.f; }
        }
        __syncthreads();
        for (int wl = 0; wl < TJ / 64; ++wl) {
            const int w = (t0 >> 6) + wl;
            if (w >= NWORDS) break;
            const int e = wl * 64 + ln;
            const int j = t0 + e;
            const float4 bj = sb[e];
            const float aj = sa[e];
            bool pA = false, pC = false;
            if (j < PRE_NMS) {   // EXACT same fp sequence as the passing round-3 kernel
                float xx1 = fmaxf(bA.x, bj.x), yy1 = fmaxf(bA.y, bj.y);
                float xx2 = fminf(bA.z, bj.z), yy2 = fminf(bA.w, bj.w);
                float inter = __fmul_rn(fmaxf(__fsub_rn(xx2, xx1), 0.f),
                                        fmaxf(__fsub_rn(yy2, yy1), 0.f));
                float den = __fadd_rn(__fsub_rn(__fadd_rn(aA, aj), inter), 1e-9f);
                pA = (j > ia) && (__fdiv_rn(inter, den) > NMS_THR);
                xx1 = fmaxf(bC.x, bj.x); yy1 = fmaxf(bC.y, bj.y);
                xx2 = fminf(bC.z, bj.z); yy2 = fminf(bC.w, bj.w);
                inter = __fmul_rn(fmaxf(__fsub_rn(xx2, xx1), 0.f),
                                  fmaxf(__fsub_rn(yy2, yy1), 0.f));
                den = __fadd_rn(__fsub_rn(__fadd_rn(aC, aj), inter), 1e-9f);
                pC = (j > ic) && (__fdiv_rn(inter, den) > NMS_THR);
            }
            unsigned long long mA = __ballot(pA), mC = __ballot(pC);
            if (ln == 0) {
                if (w >= wA) rowA[w] = mA;   // only own-diagonal-and-above words
                if (w >= wC) rowC[w] = mC;
            }
        }
        __syncthreads();
    }
}

// ------- Phase 4: windowed scan — 16 positions/window, double-buffered ------
// Per window: all 16 rows + diagonal words + boxes loaded IN PARALLEL while
// the previous window resolves entirely in registers (one 64b shfl broadcast,
// then lane-uniform scalar logic). Serial chain: ~90 windows, not ~1000 loads.
__global__ __launch_bounds__(64) void scan_kernel(const unsigned long long* __restrict__ mask,
                                                  const unsigned long long* __restrict__ validm,
                                                  const float* __restrict__ boxes,
                                                  float* __restrict__ out) {
    const int b = blockIdx.x, lane = threadIdx.x;
    const unsigned long long* mb = mask + (size_t)b * PRE_NMS * NWORDS;
    unsigned long long r0 = ~validm[(size_t)b * NWORDS + lane];
    unsigned long long r1 = (lane < NWORDS - 64) ? ~validm[(size_t)b * NWORDS + 64 + lane]
                                                 : ~0ULL;
    const bool l2ok = lane < NWORDS - 64;
    const int w2 = l2ok ? (64 + lane) : (NWORDS - 1);   // clamped in-bounds addr

    unsigned long long m0A[WIN], m1A[WIN], wwA[WIN];
    unsigned long long m0B[WIN], m1B[WIN], wwB[WIN];
    float4 boxA, boxB;
    int count = 0;

#define ISSUE(M0, M1, WW, BX, base_)                                             \
    {                                                                            \
        const int bb_ = (base_);                                                 \
        const int wI_ = bb_ >> 6;                                                \
        _Pragma("unroll")                                                        \
        for (int q = 0; q < WIN; ++q) {                                          \
            const unsigned long long* row_ = mb + (size_t)(bb_ + q) * NWORDS;    \
            M0[q] = row_[lane];                                                  \
            M1[q] = row_[w2];                                                    \
            WW[q] = row_[wI_];                                                   \
        }                                                                        \
        BX = (lane < WIN)                                                        \
                 ? ((const float4*)boxes)[(size_t)b * PRE_NMS + bb_ + lane]      \
                 : make_float4(0.f, 0.f, 0.f, 0.f);                              \
    }

#define RESOLVE(M0, M1, WW, BX, base_)                                           \
    {                                                                            \
        const int bb_ = (base_);                                                 \
        const int wR_ = bb_ >> 6, s0_ = bb_ & 63;                                \
        const unsigned long long sel_ = (wR_ < 64) ? r0 : r1;                    \
        const int srcl_ = (wR_ < 64) ? wR_ : (wR_ - 64);                         \
        const unsigned lo_ = (unsigned)__shfl((int)(unsigned)(sel_ & 0xffffffffULL), srcl_); \
        const unsigned hi_ = (unsigned)__shfl((int)(unsigned)(sel_ >> 32), srcl_);           \
        unsigned long long wword_ = ((unsigned long long)hi_ << 32) | lo_;       \
        unsigned kept_ = 0;                                                      \
        const int cbase_ = count;                                                \
        _Pragma("unroll")                                                        \
        for (int q = 0; q < WIN; ++q) {                                          \
            if (count < POST_NMS && !((wword_ >> (s0_ + q)) & 1ULL)) {           \
                kept_ |= 1u << q;                                                \
                wword_ |= WW[q];                                                 \
                ++count;                                                         \
            }                                                                    \
        }                                                                        \
        const bool v0_ = lane >= wR_;                                            \
        const bool v1_ = l2ok && (64 + lane) >= wR_;                             \
        _Pragma("unroll")                                                        \
        for (int q = 0; q < WIN; ++q) {                                          \
            if (kept_ & (1u << q)) {                                             \
                if (v0_) r0 |= M0[q];                                            \
                if (v1_) r1 |= M1[q];                                            \
            }                                                                    \
        }                                                                        \
        if (lane < WIN && (kept_ & (1u << lane))) {                              \
            const int rank_ = cbase_ + __popc(kept_ & ((1u << lane) - 1u));      \
            ((float4*)out)[(size_t)b * POST_NMS + rank_] = BX;                   \
        }                                                                        \
    }

    ISSUE(m0A, m1A, wwA, boxA, 0)
    bool useA = true;
    for (int base = 0; base < PRE_NMS && count < POST_NMS; base += WIN) {
        const int nb = (base + WIN < PRE_NMS) ? (base + WIN) : base;  // clamp: dup load, never resolved
        if (useA) {
            ISSUE(m0B, m1B, wwB, boxB, nb)
            RESOLVE(m0A, m1A, wwA, boxA, base)
        } else {
            ISSUE(m0A, m1A, wwA, boxA, nb)
            RESOLVE(m0B, m1B, wwB, boxB, base)
        }
        useA = !useA;
    }
#undef ISSUE
#undef RESOLVE
}

// ------- Final: canary writer — encodes any invariant violation in absmax ---
__global__ __launch_bounds__(64) void finalize_kernel(const unsigned* __restrict__ flags,
                                                      const unsigned* __restrict__ cgt,
                                                      const unsigned* __restrict__ cge,
                                                      const unsigned* __restrict__ ccnt,
                                                      float* __restrict__ out) {
    int b = threadIdx.x;
    if (b >= NBATCH) return;
    float canary = 0.f;
    if (ccnt[b] > CANDCAP)       canary = 111000.f;
    else if (ccnt[b] < PRE_NMS)  canary = 222000.f;
    if (flags[b] & F_SORT)       canary = 333000.f;
    if (flags[b] & F_COMP)       canary = 444000.f;
    if (flags[b] & F_OOB)        canary = 777000.f;
    if (cgt[b] != PRE_NMS - 1)   canary = 555000.f;
    if (cge[b] != PRE_NMS)       canary = 666000.f;
    if (canary != 0.f) out[(size_t)b * POST_NMS * 4] = canary;
}

extern "C" void kernel_launch(void* const* d_in, const int* in_sizes, int n_in,
                              void* d_out, int out_size, void* d_ws, size_t ws_size,
                              hipStream_t stream) {
    const float* anchors = (const float*)d_in[0];
    const float* obj     = (const float*)d_in[1];
    const float* deltas  = (const float*)d_in[2];
    const int*   imh     = (const int*)d_in[3];
    const int*   imw     = (const int*)d_in[4];
    float* out = (float*)d_out;
    char* ws = (char*)d_ws;

    size_t off = 0;
    auto alloc = [&](size_t bytes) {
        size_t o = off;
        off = (off + bytes + 511) & ~(size_t)511;
        return o;
    };
    // regions needing zero-init FIRST and contiguous -> single memset
    const size_t HIST  = alloc((size_t)NBATCH * NBINS * 4);
    const size_t TBIN  = alloc((size_t)NBATCH * 4);
    const size_t CCNT  = alloc((size_t)NBATCH * 4);
    const size_t FLAGS = alloc((size_t)NBATCH * 4);
    const size_t CGT   = alloc((size_t)NBATCH * 4);
    const size_t CGE   = alloc((size_t)NBATCH * 4);
    const size_t CAND  = alloc((size_t)NBATCH * CANDCAP * 8);
    const size_t ZEND  = off;
    const size_t TOPK  = alloc((size_t)NBATCH * PRE_NMS * 4);
    const size_t BOX   = alloc((size_t)NBATCH * PRE_NMS * 16);
    const size_t AREA  = alloc((size_t)NBATCH * PRE_NMS * 4);
    const size_t VALID = alloc((size_t)NBATCH * NWORDS * 8);
    const size_t SKEY  = alloc((size_t)NBATCH * 8);
    const size_t MASK  = alloc((size_t)NBATCH * PRE_NMS * NWORDS * 8);
    if (ws_size < off) return;

    unsigned*            hist   = (unsigned*)(ws + HIST);
    unsigned*            tbin   = (unsigned*)(ws + TBIN);
    unsigned*            ccnt   = (unsigned*)(ws + CCNT);
    unsigned*            flags  = (unsigned*)(ws + FLAGS);
    unsigned*            cgt    = (unsigned*)(ws + CGT);
    unsigned*            cge    = (unsigned*)(ws + CGE);
    unsigned long long*  cand   = (unsigned long long*)(ws + CAND);
    unsigned*            topk   = (unsigned*)(ws + TOPK);
    float*               boxes  = (float*)(ws + BOX);
    float*               areas  = (float*)(ws + AREA);
    unsigned long long*  validm = (unsigned long long*)(ws + VALID);
    unsigned long long*  skey   = (unsigned long long*)(ws + SKEY);
    unsigned long long*  maskp  = (unsigned long long*)(ws + MASK);

    hipMemsetAsync(ws, 0, ZEND, stream);   // hist+tbin+ccnt+flags+cgt+cge+cand in one node
    hipMemsetAsync(out, 0, (size_t)out_size * sizeof(float), stream);

    hist_kernel   <<<dim3(128, NBATCH), 256, 0, stream>>>(obj, hist);
    thresh_kernel <<<dim3(NBATCH), 256, 0, stream>>>(hist, tbin);
    compact_kernel<<<dim3(128, NBATCH), 256, 0, stream>>>(obj, tbin, cand, ccnt);
    sort_kernel   <<<dim3(NBATCH), 1024, 0, stream>>>(cand, obj, topk, skey, flags);
    count_kernel  <<<dim3(64, NBATCH), 256, 0, stream>>>(obj, skey, cgt, cge);
    decode_kernel <<<dim3((PRE_NMS + 255) / 256, NBATCH), 256, 0, stream>>>(
        anchors, deltas, topk, imh, imw, boxes, areas, validm);
    mask_kernel   <<<dim3((PRE_NMS / TI) * NBATCH), 256, 0, stream>>>(boxes, areas, maskp);
    scan_kernel   <<<dim3(NBATCH), 64, 0, stream>>>(maskp, validm, boxes, out);
    finalize_kernel<<<1, 64, 0, stream>>>(flags, cgt, cge, ccnt, out);
    (void)in_sizes; (void)n_in; (void)ws_size;
}

// Round 6
// 519.600 us; speedup vs baseline: 2.8857x; 1.7049x over previous
//
#include <hip/hip_runtime.h>
#include <cstdint>
#include <cmath>

#define NBATCH   8
#define NPB      500000
#define PRE_NMS  6000
#define POST_NMS 1000
#define NWORDS   94          // ceil(6000/64)
#define NBINS    16384       // 14-bit float prefix (sign+exp+5 mantissa)
#define CANDCAP  8192        // candidate cap per batch (expected ~6800 worst case)
#define BBOX_CLIP 4.135166556742356f   // log(1000/16)
#define NMS_THR  0.7f
#define TI 8                 // mask rows per block
#define TJ 512               // mask j-tile staged in LDS
#define WIN 16               // scan window (64 % WIN == 0: window never straddles words)
#define CNT_PAD 64           // counter stride in uints (256 B): one cache line per batch

#define F_SORT 1u
#define F_COMP 2u
#define F_OOB  4u

// monotone map: ascending uint <=> ascending float
__device__ __forceinline__ unsigned monot(float f) {
    unsigned b = __float_as_uint(f);
    return (b & 0x80000000u) ? ~b : (b | 0x80000000u);
}

// ---------------- Phase 1a: 16384-bin histogram of key prefix ----------------
__global__ __launch_bounds__(256) void hist_kernel(const float* __restrict__ obj,
                                                   unsigned* __restrict__ hist) {
    __shared__ unsigned lh[NBINS];   // 64 KiB
    const int b = blockIdx.y;
    for (int q = threadIdx.x; q < NBINS; q += 256) lh[q] = 0;
    __syncthreads();
    const float* p = obj + (size_t)b * NPB;
    const int stride = gridDim.x * 256;
    for (int i = blockIdx.x * 256 + threadIdx.x; i < NPB; i += stride) {
        unsigned u = monot(p[i]);
        atomicAdd(&lh[u >> 18], 1u);
    }
    __syncthreads();
    unsigned* gh = hist + (size_t)b * NBINS;
    for (int q = threadIdx.x; q < NBINS; q += 256) {
        unsigned v = lh[q];
        if (v) atomicAdd(&gh[q], v);
    }
}

// ------- Phase 1b: find threshold bin (descending cumulative >= 6000) -------
__global__ __launch_bounds__(256) void thresh_kernel(const unsigned* __restrict__ hist,
                                                     unsigned* __restrict__ tbin) {
    __shared__ unsigned part[256], pre[256];
    const int b = blockIdx.x;
    const unsigned* gh = hist + (size_t)b * NBINS;
    const int t = threadIdx.x;
    const int PER = NBINS / 256;     // 64 bins per thread
    unsigned s = 0;
    for (int d = 0; d < PER; ++d) s += gh[NBINS - 1 - (t * PER + d)];
    part[t] = s;
    __syncthreads();
    if (t == 0) {
        unsigned run = 0;
        for (int q = 0; q < 256; ++q) { pre[q] = run; run += part[q]; }
    }
    __syncthreads();
    unsigned c = pre[t];
    if (c < PRE_NMS && c + part[t] >= PRE_NMS) {
        unsigned run = c;
        for (int d = 0; d < PER; ++d) {
            int bin = NBINS - 1 - (t * PER + d);
            run += gh[bin];
            if (run >= PRE_NMS) { tbin[b] = (unsigned)bin; break; }
        }
    }
}

// ------ Phase 1c: compact candidates — WAVE-AGGREGATED atomics --------------
// One atomicAdd per wave-iteration-with-candidates (was: per candidate lane),
// counters padded to one cache line per batch. ~9k atomics vs 54k, no
// same-line sharing across batches, no per-lane same-address serialization.
__global__ __launch_bounds__(256) void compact_kernel(const float* __restrict__ obj,
                                                      const unsigned* __restrict__ tbin,
                                                      unsigned long long* __restrict__ cand,
                                                      unsigned* __restrict__ ccnt) {
    const int b = blockIdx.y;
    const unsigned T = tbin[b];
    const float* p = obj + (size_t)b * NPB;
    unsigned long long* cb = cand + (size_t)b * CANDCAP;
    const int lane = threadIdx.x & 63;
    const int stride = gridDim.x * 256;
    for (int i = blockIdx.x * 256 + threadIdx.x; i < NPB; i += stride) {
        unsigned u = monot(p[i]);
        const bool pred = (u >> 18) >= T;
        unsigned long long bal = __ballot(pred);
        if (bal == 0) continue;                      // common case: skip
        unsigned base = 0;
        // lane 0 has the smallest i in the wave -> active whenever any lane is
        if (lane == 0) base = atomicAdd(&ccnt[(size_t)b * CNT_PAD], __popcll(bal));
        base = (unsigned)__shfl((int)base, 0);
        if (pred) {
            unsigned pos = base + (unsigned)__popcll(bal & ((1ULL << lane) - 1ULL));
            if (pos < CANDCAP)  // composite: value desc, then index asc (via ~i)
                cb[pos] = ((unsigned long long)u << 32) | (unsigned)(~i);
        }
    }
}

// -------- Phase 1d: per-batch bitonic sort (descending) in 64 KiB LDS -------
// + self-verification: strict descending, composite<->input consistency.
__global__ __launch_bounds__(1024) void sort_kernel(const unsigned long long* __restrict__ cand,
                                                    const float* __restrict__ obj,
                                                    unsigned* __restrict__ topk,
                                                    unsigned long long* __restrict__ skey,
                                                    unsigned* __restrict__ flags) {
    __shared__ unsigned long long s[CANDCAP];  // 64 KiB
    const int b = blockIdx.x, t = threadIdx.x;
    const unsigned long long* cb = cand + (size_t)b * CANDCAP;
    for (int i = t; i < CANDCAP; i += 1024) s[i] = cb[i];
    __syncthreads();
    for (unsigned k = 2; k <= CANDCAP; k <<= 1) {
        for (unsigned j = k >> 1; j > 0; j >>= 1) {
            for (unsigned ii = t; ii < CANDCAP; ii += 1024) {
                unsigned l = ii ^ j;
                if (l > ii) {
                    unsigned long long a = s[ii], c = s[l];
                    bool up = (ii & k) == 0;
                    if (up ? (a < c) : (a > c)) { s[ii] = c; s[l] = a; }
                }
            }
            __syncthreads();
        }
    }
    // ---- checks + emit ----
    unsigned f = 0;
    for (int r = t; r < PRE_NMS; r += 1024) {
        unsigned long long c = s[r];
        unsigned idx = ~(unsigned)(c & 0xffffffffULL);
        if (idx >= NPB) { f |= F_OOB; idx = 0; }
        else if (monot(obj[(size_t)b * NPB + idx]) != (unsigned)(c >> 32)) f |= F_COMP;
        if (r < PRE_NMS - 1 && !(c > s[r + 1])) f |= F_SORT;
        topk[(size_t)b * PRE_NMS + r] = idx;
    }
    if (f) atomicOr(&flags[b], f);
    if (t == 0) skey[b] = s[PRE_NMS - 1];
}

// ------ independent top-k proof: #(comp > s[5999]) == 5999, #(>=) == 6000 ----
__global__ __launch_bounds__(256) void count_kernel(const float* __restrict__ obj,
                                                    const unsigned long long* __restrict__ skey,
                                                    unsigned* __restrict__ cgt,
                                                    unsigned* __restrict__ cge) {
    const int b = blockIdx.y;
    const unsigned long long C = skey[b];
    const float* p = obj + (size_t)b * NPB;
    unsigned gt = 0, ge = 0;
    const int stride = gridDim.x * 256;
    for (int i = blockIdx.x * 256 + threadIdx.x; i < NPB; i += stride) {
        unsigned long long comp = ((unsigned long long)monot(p[i]) << 32) | (unsigned)(~i);
        gt += comp > C ? 1u : 0u;
        ge += comp >= C ? 1u : 0u;
    }
    for (int o = 32; o; o >>= 1) { gt += __shfl_down(gt, o); ge += __shfl_down(ge, o); }
    if ((threadIdx.x & 63) == 0) {
        atomicAdd(&cgt[(size_t)b * CNT_PAD], gt);
        atomicAdd(&cge[(size_t)b * CNT_PAD], ge);
    }
}

// ---------------- Phase 2: decode + clip + valid (numerics FROZEN) ----------
__global__ __launch_bounds__(256) void decode_kernel(const float* __restrict__ anchors,
                                                     const float* __restrict__ deltas,
                                                     const unsigned* __restrict__ topk,
                                                     const int* __restrict__ imh,
                                                     const int* __restrict__ imw,
                                                     float* __restrict__ boxes,
                                                     float* __restrict__ areas,
                                                     unsigned long long* __restrict__ validm) {
    const int b = blockIdx.y;
    const int r = blockIdx.x * 256 + threadIdx.x;
    const bool active = r < PRE_NMS;
    int vh = imh[0], vw = imw[0];
    float ih = (vh > 0 && vh < (1 << 20)) ? (float)vh : __int_as_float(vh);
    float iw = (vw > 0 && vw < (1 << 20)) ? (float)vw : __int_as_float(vw);
    bool valid = false;
    if (active) {
        unsigned idx = topk[(size_t)b * PRE_NMS + r];
        if (idx >= NPB) idx = 0;   // canary will have fired; avoid OOB
        const float4 a = ((const float4*)anchors)[(size_t)b * NPB + idx];
        const float4 d = ((const float4*)deltas)[(size_t)b * NPB + idx];
        float wa = a.z - a.x, ha = a.w - a.y;
        float cxa = a.x + 0.5f * wa, cya = a.y + 0.5f * ha;  // 0.5*x exact: fma-safe
        float dw = fminf(d.z, BBOX_CLIP), dh = fminf(d.w, BBOX_CLIP);
        float cx = __fadd_rn(__fmul_rn(d.x, wa), cxa);
        float cy = __fadd_rn(__fmul_rn(d.y, ha), cya);
        float ew = (float)::exp((double)dw), eh = (float)::exp((double)dh);
        float w = __fmul_rn(ew, wa), h = __fmul_rn(eh, ha);
        float x1 = cx - 0.5f * w, y1 = cy - 0.5f * h;
        float x2 = cx + 0.5f * w, y2 = cy + 0.5f * h;
        x1 = fminf(fmaxf(x1, 0.f), iw); y1 = fminf(fmaxf(y1, 0.f), ih);
        x2 = fminf(fmaxf(x2, 0.f), iw); y2 = fminf(fmaxf(y2, 0.f), ih);
        valid = (x2 - x1 >= 1.0f) && (y2 - y1 >= 1.0f);
        ((float4*)boxes)[(size_t)b * PRE_NMS + r] = make_float4(x1, y1, x2, y2);
        areas[(size_t)b * PRE_NMS + r] = __fmul_rn(x2 - x1, y2 - y1);
    }
    unsigned long long bal = __ballot(valid);
    int w = r >> 6;
    if ((threadIdx.x & 63) == 0 && w < NWORDS) validm[(size_t)b * NWORDS + w] = bal;
}

// ------- Phase 3: suppression bitmask, UPPER-TRIANGLE words only -----------
__global__ __launch_bounds__(256) void mask_kernel(const float* __restrict__ boxes,
                                                   const float* __restrict__ areas,
                                                   unsigned long long* __restrict__ mask) {
    __shared__ float4 sb[TJ];
    __shared__ float  sa[TJ];
    const int b = blockIdx.x & 7;            // XCD pin: block -> XCD round-robin
    const int i0 = (blockIdx.x >> 3) * TI;
    const int jbase = (i0 >> 6) << 6;
    const int wv = threadIdx.x >> 6, ln = threadIdx.x & 63;
    const int ia = i0 + 2 * wv, ic = ia + 1;  // 2 rows per wave; 6000 % 8 == 0
    const float4 bA = ((const float4*)boxes)[(size_t)b * PRE_NMS + ia];
    const float4 bC = ((const float4*)boxes)[(size_t)b * PRE_NMS + ic];
    const float aA = areas[(size_t)b * PRE_NMS + ia];
    const float aC = areas[(size_t)b * PRE_NMS + ic];
    unsigned long long* rowA = mask + ((size_t)b * PRE_NMS + ia) * NWORDS;
    unsigned long long* rowC = mask + ((size_t)b * PRE_NMS + ic) * NWORDS;
    const int wA = ia >> 6, wC = ic >> 6;
    for (int t0 = jbase; t0 < NWORDS * 64; t0 += TJ) {
        for (int e = threadIdx.x; e < TJ; e += 256) {
            int j = t0 + e;
            if (j < PRE_NMS) {
                sb[e] = ((const float4*)boxes)[(size_t)b * PRE_NMS + j];
                sa[e] = areas[(size_t)b * PRE_NMS + j];
            } else { sb[e] = make_float4(0.f, 0.f, 0.f, 0.f); sa[e] = 0.f; }
        }
        __syncthreads();
        for (int wl = 0; wl < TJ / 64; ++wl) {
            const int w = (t0 >> 6) + wl;
            if (w >= NWORDS) break;
            const int e = wl * 64 + ln;
            const int j = t0 + e;
            const float4 bj = sb[e];
            const float aj = sa[e];
            bool pA = false, pC = false;
            if (j < PRE_NMS) {   // EXACT same fp sequence as the passing round-3 kernel
                float xx1 = fmaxf(bA.x, bj.x), yy1 = fmaxf(bA.y, bj.y);
                float xx2 = fminf(bA.z, bj.z), yy2 = fminf(bA.w, bj.w);
                float inter = __fmul_rn(fmaxf(__fsub_rn(xx2, xx1), 0.f),
                                        fmaxf(__fsub_rn(yy2, yy1), 0.f));
                float den = __fadd_rn(__fsub_rn(__fadd_rn(aA, aj), inter), 1e-9f);
                pA = (j > ia) && (__fdiv_rn(inter, den) > NMS_THR);
                xx1 = fmaxf(bC.x, bj.x); yy1 = fmaxf(bC.y, bj.y);
                xx2 = fminf(bC.z, bj.z); yy2 = fminf(bC.w, bj.w);
                inter = __fmul_rn(fmaxf(__fsub_rn(xx2, xx1), 0.f),
                                  fmaxf(__fsub_rn(yy2, yy1), 0.f));
                den = __fadd_rn(__fsub_rn(__fadd_rn(aC, aj), inter), 1e-9f);
                pC = (j > ic) && (__fdiv_rn(inter, den) > NMS_THR);
            }
            unsigned long long mA = __ballot(pA), mC = __ballot(pC);
            if (ln == 0) {
                if (w >= wA) rowA[w] = mA;   // only own-diagonal-and-above words
                if (w >= wC) rowC[w] = mC;
            }
        }
        __syncthreads();
    }
}

// ------- Phase 4: windowed scan — 16 positions/window, double-buffered ------
__global__ __launch_bounds__(64) void scan_kernel(const unsigned long long* __restrict__ mask,
                                                  const unsigned long long* __restrict__ validm,
                                                  const float* __restrict__ boxes,
                                                  float* __restrict__ out) {
    const int b = blockIdx.x, lane = threadIdx.x;
    const unsigned long long* mb = mask + (size_t)b * PRE_NMS * NWORDS;
    unsigned long long r0 = ~validm[(size_t)b * NWORDS + lane];
    unsigned long long r1 = (lane < NWORDS - 64) ? ~validm[(size_t)b * NWORDS + 64 + lane]
                                                 : ~0ULL;
    const bool l2ok = lane < NWORDS - 64;
    const int w2 = l2ok ? (64 + lane) : (NWORDS - 1);   // clamped in-bounds addr

    unsigned long long m0A[WIN], m1A[WIN], wwA[WIN];
    unsigned long long m0B[WIN], m1B[WIN], wwB[WIN];
    float4 boxA, boxB;
    int count = 0;

#define ISSUE(M0, M1, WW, BX, base_)                                             \
    {                                                                            \
        const int bb_ = (base_);                                                 \
        const int wI_ = bb_ >> 6;                                                \
        _Pragma("unroll")                                                        \
        for (int q = 0; q < WIN; ++q) {                                          \
            const unsigned long long* row_ = mb + (size_t)(bb_ + q) * NWORDS;    \
            M0[q] = row_[lane];                                                  \
            M1[q] = row_[w2];                                                    \
            WW[q] = row_[wI_];                                                   \
        }                                                                        \
        BX = (lane < WIN)                                                        \
                 ? ((const float4*)boxes)[(size_t)b * PRE_NMS + bb_ + lane]      \
                 : make_float4(0.f, 0.f, 0.f, 0.f);                              \
    }

#define RESOLVE(M0, M1, WW, BX, base_)                                           \
    {                                                                            \
        const int bb_ = (base_);                                                 \
        const int wR_ = bb_ >> 6, s0_ = bb_ & 63;                                \
        const unsigned long long sel_ = (wR_ < 64) ? r0 : r1;                    \
        const int srcl_ = (wR_ < 64) ? wR_ : (wR_ - 64);                         \
        const unsigned lo_ = (unsigned)__shfl((int)(unsigned)(sel_ & 0xffffffffULL), srcl_); \
        const unsigned hi_ = (unsigned)__shfl((int)(unsigned)(sel_ >> 32), srcl_);           \
        unsigned long long wword_ = ((unsigned long long)hi_ << 32) | lo_;       \
        unsigned kept_ = 0;                                                      \
        const int cbase_ = count;                                                \
        _Pragma("unroll")                                                        \
        for (int q = 0; q < WIN; ++q) {                                          \
            if (count < POST_NMS && !((wword_ >> (s0_ + q)) & 1ULL)) {           \
                kept_ |= 1u << q;                                                \
                wword_ |= WW[q];                                                 \
                ++count;                                                         \
            }                                                                    \
        }                                                                        \
        const bool v0_ = lane >= wR_;                                            \
        const bool v1_ = l2ok && (64 + lane) >= wR_;                             \
        _Pragma("unroll")                                                        \
        for (int q = 0; q < WIN; ++q) {                                          \
            if (kept_ & (1u << q)) {                                             \
                if (v0_) r0 |= M0[q];                                            \
                if (v1_) r1 |= M1[q];                                            \
            }                                                                    \
        }                                                                        \
        if (lane < WIN && (kept_ & (1u << lane))) {                              \
            const int rank_ = cbase_ + __popc(kept_ & ((1u << lane) - 1u));      \
            ((float4*)out)[(size_t)b * POST_NMS + rank_] = BX;                   \
        }                                                                        \
    }

    ISSUE(m0A, m1A, wwA, boxA, 0)
    bool useA = true;
    for (int base = 0; base < PRE_NMS && count < POST_NMS; base += WIN) {
        const int nb = (base + WIN < PRE_NMS) ? (base + WIN) : base;  // clamp: dup load, never resolved
        if (useA) {
            ISSUE(m0B, m1B, wwB, boxB, nb)
            RESOLVE(m0A, m1A, wwA, boxA, base)
        } else {
            ISSUE(m0A, m1A, wwA, boxA, nb)
            RESOLVE(m0B, m1B, wwB, boxB, base)
        }
        useA = !useA;
    }
#undef ISSUE
#undef RESOLVE
}

// ------- Final: canary writer — encodes any invariant violation in absmax ---
__global__ __launch_bounds__(64) void finalize_kernel(const unsigned* __restrict__ flags,
                                                      const unsigned* __restrict__ cgt,
                                                      const unsigned* __restrict__ cge,
                                                      const unsigned* __restrict__ ccnt,
                                                      float* __restrict__ out) {
    int b = threadIdx.x;
    if (b >= NBATCH) return;
    float canary = 0.f;
    if (ccnt[(size_t)b * CNT_PAD] > CANDCAP)       canary = 111000.f;
    else if (ccnt[(size_t)b * CNT_PAD] < PRE_NMS)  canary = 222000.f;
    if (flags[b] & F_SORT)                         canary = 333000.f;
    if (flags[b] & F_COMP)                         canary = 444000.f;
    if (flags[b] & F_OOB)                          canary = 777000.f;
    if (cgt[(size_t)b * CNT_PAD] != PRE_NMS - 1)   canary = 555000.f;
    if (cge[(size_t)b * CNT_PAD] != PRE_NMS)       canary = 666000.f;
    if (canary != 0.f) out[(size_t)b * POST_NMS * 4] = canary;
}

extern "C" void kernel_launch(void* const* d_in, const int* in_sizes, int n_in,
                              void* d_out, int out_size, void* d_ws, size_t ws_size,
                              hipStream_t stream) {
    const float* anchors = (const float*)d_in[0];
    const float* obj     = (const float*)d_in[1];
    const float* deltas  = (const float*)d_in[2];
    const int*   imh     = (const int*)d_in[3];
    const int*   imw     = (const int*)d_in[4];
    float* out = (float*)d_out;
    char* ws = (char*)d_ws;

    size_t off = 0;
    auto alloc = [&](size_t bytes) {
        size_t o = off;
        off = (off + bytes + 511) & ~(size_t)511;
        return o;
    };
    // regions needing zero-init FIRST and contiguous -> single memset
    const size_t HIST  = alloc((size_t)NBATCH * NBINS * 4);
    const size_t TBIN  = alloc((size_t)NBATCH * 4);
    const size_t CCNT  = alloc((size_t)NBATCH * CNT_PAD * 4);
    const size_t FLAGS = alloc((size_t)NBATCH * 4);
    const size_t CGT   = alloc((size_t)NBATCH * CNT_PAD * 4);
    const size_t CGE   = alloc((size_t)NBATCH * CNT_PAD * 4);
    const size_t CAND  = alloc((size_t)NBATCH * CANDCAP * 8);
    const size_t ZEND  = off;
    const size_t TOPK  = alloc((size_t)NBATCH * PRE_NMS * 4);
    const size_t BOX   = alloc((size_t)NBATCH * PRE_NMS * 16);
    const size_t AREA  = alloc((size_t)NBATCH * PRE_NMS * 4);
    const size_t VALID = alloc((size_t)NBATCH * NWORDS * 8);
    const size_t SKEY  = alloc((size_t)NBATCH * 8);
    const size_t MASK  = alloc((size_t)NBATCH * PRE_NMS * NWORDS * 8);
    if (ws_size < off) return;

    unsigned*            hist   = (unsigned*)(ws + HIST);
    unsigned*            tbin   = (unsigned*)(ws + TBIN);
    unsigned*            ccnt   = (unsigned*)(ws + CCNT);
    unsigned*            flags  = (unsigned*)(ws + FLAGS);
    unsigned*            cgt    = (unsigned*)(ws + CGT);
    unsigned*            cge    = (unsigned*)(ws + CGE);
    unsigned long long*  cand   = (unsigned long long*)(ws + CAND);
    unsigned*            topk   = (unsigned*)(ws + TOPK);
    float*               boxes  = (float*)(ws + BOX);
    float*               areas  = (float*)(ws + AREA);
    unsigned long long*  validm = (unsigned long long*)(ws + VALID);
    unsigned long long*  skey   = (unsigned long long*)(ws + SKEY);
    unsigned long long*  maskp  = (unsigned long long*)(ws + MASK);

    hipMemsetAsync(ws, 0, ZEND, stream);   // hist+tbin+counters+cand in one node
    hipMemsetAsync(out, 0, (size_t)out_size * sizeof(float), stream);

    hist_kernel   <<<dim3(128, NBATCH), 256, 0, stream>>>(obj, hist);
    thresh_kernel <<<dim3(NBATCH), 256, 0, stream>>>(hist, tbin);
    compact_kernel<<<dim3(128, NBATCH), 256, 0, stream>>>(obj, tbin, cand, ccnt);
    sort_kernel   <<<dim3(NBATCH), 1024, 0, stream>>>(cand, obj, topk, skey, flags);
    count_kernel  <<<dim3(64, NBATCH), 256, 0, stream>>>(obj, skey, cgt, cge);
    decode_kernel <<<dim3((PRE_NMS + 255) / 256, NBATCH), 256, 0, stream>>>(
        anchors, deltas, topk, imh, imw, boxes, areas, validm);
    mask_kernel   <<<dim3((PRE_NMS / TI) * NBATCH), 256, 0, stream>>>(boxes, areas, maskp);
    scan_kernel   <<<dim3(NBATCH), 64, 0, stream>>>(maskp, validm, boxes, out);
    finalize_kernel<<<1, 64, 0, stream>>>(flags, cgt, cge, ccnt, out);
    (void)in_sizes; (void)n_in; (void)ws_size;
}

// Round 7
// 448.967 us; speedup vs baseline: 3.3397x; 1.1573x over previous
//
#include <hip/hip_runtime.h>
#include <cstdint>
#include <cmath>

#define NBATCH   8
#define NPB      500000
#define PRE_NMS  6000
#define POST_NMS 1000
#define NWORDS   94          // ceil(6000/64)
#define NBINS    16384       // 14-bit float prefix (sign+exp+5 mantissa)
#define CANDCAP  8192        // candidate cap per batch (expected ~6800 worst case)
#define BBOX_CLIP 4.135166556742356f   // log(1000/16)
#define NMS_THR  0.7f
#define TI 8                 // mask rows per block
#define TJ 512               // mask j-tile staged in LDS
#define WIN 16               // scan window (64 % WIN == 0: window never straddles words)
#define CNT_PAD 64           // counter stride in uints (256 B): one cache line per batch

#define F_SORT 1u
#define F_COMP 2u
#define F_OOB  4u

// monotone map: ascending uint <=> ascending float
__device__ __forceinline__ unsigned monot(float f) {
    unsigned b = __float_as_uint(f);
    return (b & 0x80000000u) ? ~b : (b | 0x80000000u);
}

// ---------------- Phase 1a: 16384-bin histogram of key prefix ----------------
__global__ __launch_bounds__(256) void hist_kernel(const float* __restrict__ obj,
                                                   unsigned* __restrict__ hist) {
    __shared__ unsigned lh[NBINS];   // 64 KiB
    const int b = blockIdx.y;
    for (int q = threadIdx.x; q < NBINS; q += 256) lh[q] = 0;
    __syncthreads();
    const float* p = obj + (size_t)b * NPB;
    const int stride = gridDim.x * 256;
    for (int i = blockIdx.x * 256 + threadIdx.x; i < NPB; i += stride) {
        unsigned u = monot(p[i]);
        atomicAdd(&lh[u >> 18], 1u);
    }
    __syncthreads();
    unsigned* gh = hist + (size_t)b * NBINS;
    for (int q = threadIdx.x; q < NBINS; q += 256) {
        unsigned v = lh[q];
        if (v) atomicAdd(&gh[q], v);
    }
}

// ------- Phase 1b: find threshold bin (descending cumulative >= 6000) -------
__global__ __launch_bounds__(256) void thresh_kernel(const unsigned* __restrict__ hist,
                                                     unsigned* __restrict__ tbin) {
    __shared__ unsigned part[256], pre[256];
    const int b = blockIdx.x;
    const unsigned* gh = hist + (size_t)b * NBINS;
    const int t = threadIdx.x;
    const int PER = NBINS / 256;     // 64 bins per thread
    unsigned s = 0;
    for (int d = 0; d < PER; ++d) s += gh[NBINS - 1 - (t * PER + d)];
    part[t] = s;
    __syncthreads();
    if (t == 0) {
        unsigned run = 0;
        for (int q = 0; q < 256; ++q) { pre[q] = run; run += part[q]; }
    }
    __syncthreads();
    unsigned c = pre[t];
    if (c < PRE_NMS && c + part[t] >= PRE_NMS) {
        unsigned run = c;
        for (int d = 0; d < PER; ++d) {
            int bin = NBINS - 1 - (t * PER + d);
            run += gh[bin];
            if (run >= PRE_NMS) { tbin[b] = (unsigned)bin; break; }
        }
    }
}

// ------ Phase 1c: compact candidates — WAVE-AGGREGATED atomics --------------
__global__ __launch_bounds__(256) void compact_kernel(const float* __restrict__ obj,
                                                      const unsigned* __restrict__ tbin,
                                                      unsigned long long* __restrict__ cand,
                                                      unsigned* __restrict__ ccnt) {
    const int b = blockIdx.y;
    const unsigned T = tbin[b];
    const float* p = obj + (size_t)b * NPB;
    unsigned long long* cb = cand + (size_t)b * CANDCAP;
    const int lane = threadIdx.x & 63;
    const int stride = gridDim.x * 256;
    for (int i = blockIdx.x * 256 + threadIdx.x; i < NPB; i += stride) {
        unsigned u = monot(p[i]);
        const bool pred = (u >> 18) >= T;
        unsigned long long bal = __ballot(pred);
        if (bal == 0) continue;                      // common case: skip
        unsigned base = 0;
        // lane 0 has the smallest i in the wave -> active whenever any lane is
        if (lane == 0) base = atomicAdd(&ccnt[(size_t)b * CNT_PAD], __popcll(bal));
        base = (unsigned)__shfl((int)base, 0);
        if (pred) {
            unsigned pos = base + (unsigned)__popcll(bal & ((1ULL << lane) - 1ULL));
            if (pos < CANDCAP)  // composite: value desc, then index asc (via ~i)
                cb[pos] = ((unsigned long long)u << 32) | (unsigned)(~i);
        }
    }
}

// -------- Phase 1d: per-batch bitonic sort (descending) in 64 KiB LDS -------
// + self-verification: strict descending, composite<->input consistency.
__global__ __launch_bounds__(1024) void sort_kernel(const unsigned long long* __restrict__ cand,
                                                    const float* __restrict__ obj,
                                                    unsigned* __restrict__ topk,
                                                    unsigned* __restrict__ flags) {
    __shared__ unsigned long long s[CANDCAP];  // 64 KiB
    const int b = blockIdx.x, t = threadIdx.x;
    const unsigned long long* cb = cand + (size_t)b * CANDCAP;
    for (int i = t; i < CANDCAP; i += 1024) s[i] = cb[i];
    __syncthreads();
    for (unsigned k = 2; k <= CANDCAP; k <<= 1) {
        for (unsigned j = k >> 1; j > 0; j >>= 1) {
            for (unsigned ii = t; ii < CANDCAP; ii += 1024) {
                unsigned l = ii ^ j;
                if (l > ii) {
                    unsigned long long a = s[ii], c = s[l];
                    bool up = (ii & k) == 0;
                    if (up ? (a < c) : (a > c)) { s[ii] = c; s[l] = a; }
                }
            }
            __syncthreads();
        }
    }
    // ---- checks + emit ----
    unsigned f = 0;
    for (int r = t; r < PRE_NMS; r += 1024) {
        unsigned long long c = s[r];
        unsigned idx = ~(unsigned)(c & 0xffffffffULL);
        if (idx >= NPB) { f |= F_OOB; idx = 0; }
        else if (monot(obj[(size_t)b * NPB + idx]) != (unsigned)(c >> 32)) f |= F_COMP;
        if (r < PRE_NMS - 1 && !(c > s[r + 1])) f |= F_SORT;
        topk[(size_t)b * PRE_NMS + r] = idx;
    }
    if (f) atomicOr(&flags[b], f);
}

// ---------------- Phase 2: decode + clip + valid (numerics FROZEN) ----------
__global__ __launch_bounds__(256) void decode_kernel(const float* __restrict__ anchors,
                                                     const float* __restrict__ deltas,
                                                     const unsigned* __restrict__ topk,
                                                     const int* __restrict__ imh,
                                                     const int* __restrict__ imw,
                                                     float* __restrict__ boxes,
                                                     float* __restrict__ areas,
                                                     unsigned long long* __restrict__ validm) {
    const int b = blockIdx.y;
    const int r = blockIdx.x * 256 + threadIdx.x;
    const bool active = r < PRE_NMS;
    int vh = imh[0], vw = imw[0];
    float ih = (vh > 0 && vh < (1 << 20)) ? (float)vh : __int_as_float(vh);
    float iw = (vw > 0 && vw < (1 << 20)) ? (float)vw : __int_as_float(vw);
    bool valid = false;
    if (active) {
        unsigned idx = topk[(size_t)b * PRE_NMS + r];
        if (idx >= NPB) idx = 0;   // canary will have fired; avoid OOB
        const float4 a = ((const float4*)anchors)[(size_t)b * NPB + idx];
        const float4 d = ((const float4*)deltas)[(size_t)b * NPB + idx];
        float wa = a.z - a.x, ha = a.w - a.y;
        float cxa = a.x + 0.5f * wa, cya = a.y + 0.5f * ha;  // 0.5*x exact: fma-safe
        float dw = fminf(d.z, BBOX_CLIP), dh = fminf(d.w, BBOX_CLIP);
        float cx = __fadd_rn(__fmul_rn(d.x, wa), cxa);
        float cy = __fadd_rn(__fmul_rn(d.y, ha), cya);
        float ew = (float)::exp((double)dw), eh = (float)::exp((double)dh);
        float w = __fmul_rn(ew, wa), h = __fmul_rn(eh, ha);
        float x1 = cx - 0.5f * w, y1 = cy - 0.5f * h;
        float x2 = cx + 0.5f * w, y2 = cy + 0.5f * h;
        x1 = fminf(fmaxf(x1, 0.f), iw); y1 = fminf(fmaxf(y1, 0.f), ih);
        x2 = fminf(fmaxf(x2, 0.f), iw); y2 = fminf(fmaxf(y2, 0.f), ih);
        valid = (x2 - x1 >= 1.0f) && (y2 - y1 >= 1.0f);
        ((float4*)boxes)[(size_t)b * PRE_NMS + r] = make_float4(x1, y1, x2, y2);
        areas[(size_t)b * PRE_NMS + r] = __fmul_rn(x2 - x1, y2 - y1);
    }
    unsigned long long bal = __ballot(valid);
    int w = r >> 6;
    if ((threadIdx.x & 63) == 0 && w < NWORDS) validm[(size_t)b * NWORDS + w] = bal;
}

// ------- Phase 3: suppression bitmask, UPPER-TRIANGLE words only -----------
__global__ __launch_bounds__(256) void mask_kernel(const float* __restrict__ boxes,
                                                   const float* __restrict__ areas,
                                                   unsigned long long* __restrict__ mask) {
    __shared__ float4 sb[TJ];
    __shared__ float  sa[TJ];
    const int b = blockIdx.x & 7;            // XCD pin: block -> XCD round-robin
    const int i0 = (blockIdx.x >> 3) * TI;
    const int jbase = (i0 >> 6) << 6;
    const int wv = threadIdx.x >> 6, ln = threadIdx.x & 63;
    const int ia = i0 + 2 * wv, ic = ia + 1;  // 2 rows per wave; 6000 % 8 == 0
    const float4 bA = ((const float4*)boxes)[(size_t)b * PRE_NMS + ia];
    const float4 bC = ((const float4*)boxes)[(size_t)b * PRE_NMS + ic];
    const float aA = areas[(size_t)b * PRE_NMS + ia];
    const float aC = areas[(size_t)b * PRE_NMS + ic];
    unsigned long long* rowA = mask + ((size_t)b * PRE_NMS + ia) * NWORDS;
    unsigned long long* rowC = mask + ((size_t)b * PRE_NMS + ic) * NWORDS;
    const int wA = ia >> 6, wC = ic >> 6;
    for (int t0 = jbase; t0 < NWORDS * 64; t0 += TJ) {
        for (int e = threadIdx.x; e < TJ; e += 256) {
            int j = t0 + e;
            if (j < PRE_NMS) {
                sb[e] = ((const float4*)boxes)[(size_t)b * PRE_NMS + j];
                sa[e] = areas[(size_t)b * PRE_NMS + j];
            } else { sb[e] = make_float4(0.f, 0.f, 0.f, 0.f); sa[e] = 0.f; }
        }
        __syncthreads();
        for (int wl = 0; wl < TJ / 64; ++wl) {
            const int w = (t0 >> 6) + wl;
            if (w >= NWORDS) break;
            const int e = wl * 64 + ln;
            const int j = t0 + e;
            const float4 bj = sb[e];
            const float aj = sa[e];
            bool pA = false, pC = false;
            if (j < PRE_NMS) {   // EXACT same fp sequence as the passing round-3 kernel
                float xx1 = fmaxf(bA.x, bj.x), yy1 = fmaxf(bA.y, bj.y);
                float xx2 = fminf(bA.z, bj.z), yy2 = fminf(bA.w, bj.w);
                float inter = __fmul_rn(fmaxf(__fsub_rn(xx2, xx1), 0.f),
                                        fmaxf(__fsub_rn(yy2, yy1), 0.f));
                float den = __fadd_rn(__fsub_rn(__fadd_rn(aA, aj), inter), 1e-9f);
                pA = (j > ia) && (__fdiv_rn(inter, den) > NMS_THR);
                xx1 = fmaxf(bC.x, bj.x); yy1 = fmaxf(bC.y, bj.y);
                xx2 = fminf(bC.z, bj.z); yy2 = fminf(bC.w, bj.w);
                inter = __fmul_rn(fmaxf(__fsub_rn(xx2, xx1), 0.f),
                                  fmaxf(__fsub_rn(yy2, yy1), 0.f));
                den = __fadd_rn(__fsub_rn(__fadd_rn(aC, aj), inter), 1e-9f);
                pC = (j > ic) && (__fdiv_rn(inter, den) > NMS_THR);
            }
            unsigned long long mA = __ballot(pA), mC = __ballot(pC);
            if (ln == 0) {
                if (w >= wA) rowA[w] = mA;   // only own-diagonal-and-above words
                if (w >= wC) rowC[w] = mC;
            }
        }
        __syncthreads();
    }
}

// ------- Phase 4: windowed scan v3 — depth-3 pipeline, dwordx4 rows ---------
// Lane l holds row words 2l,2l+1 (uint4 per row); diagonal word W[q] uniform.
// All array indices are compile-time (rule #20): decision/OR loops unrolled.
// 33 loads/window; depth 3 -> ~66 outstanding (vmcnt cap 63: negligible).
__global__ __launch_bounds__(64) void scan_kernel(const unsigned long long* __restrict__ mask,
                                                  const unsigned long long* __restrict__ validm,
                                                  const float* __restrict__ boxes,
                                                  const unsigned* __restrict__ flags,
                                                  const unsigned* __restrict__ ccnt,
                                                  float* __restrict__ out) {
    const int b = blockIdx.x, lane = threadIdx.x;
    const unsigned long long* mb = mask + (size_t)b * PRE_NMS * NWORDS;
    const int w0 = 2 * lane, w1 = 2 * lane + 1;
    unsigned long long r_lo = (w0 < NWORDS) ? ~validm[(size_t)b * NWORDS + w0] : ~0ULL;
    unsigned long long r_hi = (w1 < NWORDS) ? ~validm[(size_t)b * NWORDS + w1] : ~0ULL;
    int count = 0;

    uint4 MA[WIN], MB[WIN], MC[WIN];
    unsigned long long WA[WIN], WB[WIN], WC[WIN];
    float4 bxA, bxB, bxC;

#define ISSUE(M, W, BX, base_)                                                   \
    {                                                                            \
        const int bb_ = (base_);                                                 \
        const char* rb_ = (const char*)(mb + (size_t)bb_ * NWORDS);              \
        const int wI_ = bb_ >> 6;                                                \
        _Pragma("unroll")                                                        \
        for (int q = 0; q < WIN; ++q) {                                          \
            const char* rp_ = rb_ + (size_t)q * (NWORDS * 8);                    \
            M[q] = *(const uint4*)(rp_ + (size_t)lane * 16);                     \
            W[q] = *(const unsigned long long*)(rp_ + (size_t)wI_ * 8);          \
        }                                                                        \
        BX = (lane < WIN)                                                        \
                 ? ((const float4*)boxes)[(size_t)b * PRE_NMS + bb_ + lane]      \
                 : make_float4(0.f, 0.f, 0.f, 0.f);                              \
    }

#define RESOLVE(M, W, BX, base_)                                                 \
    {                                                                            \
        const int bb_ = (base_);                                                 \
        const int wR_ = bb_ >> 6, s0_ = bb_ & 63;                                \
        const unsigned long long sel_ = (wR_ & 1) ? r_hi : r_lo;                 \
        const int srcl_ = wR_ >> 1;                                              \
        const unsigned lo_ = (unsigned)__shfl((int)(unsigned)(sel_ & 0xffffffffULL), srcl_); \
        const unsigned hi_ = (unsigned)__shfl((int)(unsigned)(sel_ >> 32), srcl_);           \
        const unsigned long long ww_ = ((unsigned long long)hi_ << 32) | lo_;    \
        unsigned cand_ = (unsigned)((~ww_) >> s0_) & 0xFFFFu;                    \
        unsigned kept_ = 0;                                                      \
        const int cb_ = count;                                                   \
        _Pragma("unroll")                                                        \
        for (int q = 0; q < WIN; ++q) {                                          \
            if (((cand_ >> q) & 1u) && count < POST_NMS) {                       \
                kept_ |= 1u << q; ++count;                                       \
                cand_ &= ~(unsigned)(W[q] >> s0_);                               \
            }                                                                    \
        }                                                                        \
        const bool v0_ = (w0 >= wR_), v1_ = (w1 >= wR_);                         \
        _Pragma("unroll")                                                        \
        for (int q = 0; q < WIN; ++q) {                                          \
            if (kept_ & (1u << q)) {                                             \
                const uint4 m_ = M[q];                                           \
                if (v0_) r_lo |= ((unsigned long long)m_.y << 32) | m_.x;        \
                if (v1_) r_hi |= ((unsigned long long)m_.w << 32) | m_.z;        \
            }                                                                    \
        }                                                                        \
        if (lane < WIN && (kept_ & (1u << lane))) {                              \
            const int rank_ = cb_ + __popc(kept_ & ((1u << lane) - 1u));         \
            ((float4*)out)[(size_t)b * POST_NMS + rank_] = BX;                   \
        }                                                                        \
    }

    ISSUE(MA, WA, bxA, 0)
    ISSUE(MB, WB, bxB, WIN)
    bool done = false;
    for (int base = 0; base < PRE_NMS && !done; base += 3 * WIN) {
        const int n2 = base + 2 * WIN;
        ISSUE(MC, WC, bxC, (n2 < PRE_NMS) ? n2 : 0)
        RESOLVE(MA, WA, bxA, base)
        done = (count >= POST_NMS);
        if (!done) {
            const int n3 = base + 3 * WIN;
            ISSUE(MA, WA, bxA, (n3 < PRE_NMS) ? n3 : 0)
            RESOLVE(MB, WB, bxB, base + WIN)
            done = (count >= POST_NMS);
        }
        if (!done) {
            const int n4 = base + 4 * WIN;
            ISSUE(MB, WB, bxB, (n4 < PRE_NMS) ? n4 : 0)
            RESOLVE(MC, WC, bxC, base + 2 * WIN)
            done = (count >= POST_NMS);
        }
    }
#undef ISSUE
#undef RESOLVE

    // merged finalize: canary on invariant violation (absmax names the stage)
    if (lane == 0) {
        float canary = 0.f;
        const unsigned cc = ccnt[(size_t)b * CNT_PAD];
        const unsigned fl = flags[b];
        if (cc > CANDCAP)       canary = 111000.f;
        else if (cc < PRE_NMS)  canary = 222000.f;
        if (fl & F_SORT)        canary = 333000.f;
        if (fl & F_COMP)        canary = 444000.f;
        if (fl & F_OOB)         canary = 777000.f;
        if (canary != 0.f) out[(size_t)b * POST_NMS * 4] = canary;
    }
}

extern "C" void kernel_launch(void* const* d_in, const int* in_sizes, int n_in,
                              void* d_out, int out_size, void* d_ws, size_t ws_size,
                              hipStream_t stream) {
    const float* anchors = (const float*)d_in[0];
    const float* obj     = (const float*)d_in[1];
    const float* deltas  = (const float*)d_in[2];
    const int*   imh     = (const int*)d_in[3];
    const int*   imw     = (const int*)d_in[4];
    float* out = (float*)d_out;
    char* ws = (char*)d_ws;

    size_t off = 0;
    auto alloc = [&](size_t bytes) {
        size_t o = off;
        off = (off + bytes + 511) & ~(size_t)511;
        return o;
    };
    // regions needing zero-init FIRST and contiguous -> single memset
    const size_t HIST  = alloc((size_t)NBATCH * NBINS * 4);
    const size_t TBIN  = alloc((size_t)NBATCH * 4);
    const size_t CCNT  = alloc((size_t)NBATCH * CNT_PAD * 4);
    const size_t FLAGS = alloc((size_t)NBATCH * 4);
    const size_t CAND  = alloc((size_t)NBATCH * CANDCAP * 8);
    const size_t ZEND  = off;
    const size_t TOPK  = alloc((size_t)NBATCH * PRE_NMS * 4);
    const size_t BOX   = alloc((size_t)NBATCH * PRE_NMS * 16);
    const size_t AREA  = alloc((size_t)NBATCH * PRE_NMS * 4);
    const size_t VALID = alloc((size_t)NBATCH * NWORDS * 8);
    const size_t MASK  = alloc((size_t)NBATCH * PRE_NMS * NWORDS * 8);
    (void)alloc(1024);   // pad: scan's dwordx4 row reads overrun rows by <=272B
    if (ws_size < off) return;

    unsigned*            hist   = (unsigned*)(ws + HIST);
    unsigned*            tbin   = (unsigned*)(ws + TBIN);
    unsigned*            ccnt   = (unsigned*)(ws + CCNT);
    unsigned*            flags  = (unsigned*)(ws + FLAGS);
    unsigned long long*  cand   = (unsigned long long*)(ws + CAND);
    unsigned*            topk   = (unsigned*)(ws + TOPK);
    float*               boxes  = (float*)(ws + BOX);
    float*               areas  = (float*)(ws + AREA);
    unsigned long long*  validm = (unsigned long long*)(ws + VALID);
    unsigned long long*  maskp  = (unsigned long long*)(ws + MASK);

    hipMemsetAsync(ws, 0, ZEND, stream);   // hist+tbin+ccnt+flags+cand in one node
    hipMemsetAsync(out, 0, (size_t)out_size * sizeof(float), stream);

    hist_kernel   <<<dim3(32, NBATCH), 256, 0, stream>>>(obj, hist);
    thresh_kernel <<<dim3(NBATCH), 256, 0, stream>>>(hist, tbin);
    compact_kernel<<<dim3(128, NBATCH), 256, 0, stream>>>(obj, tbin, cand, ccnt);
    sort_kernel   <<<dim3(NBATCH), 1024, 0, stream>>>(cand, obj, topk, flags);
    decode_kernel <<<dim3((PRE_NMS + 255) / 256, NBATCH), 256, 0, stream>>>(
        anchors, deltas, topk, imh, imw, boxes, areas, validm);
    mask_kernel   <<<dim3((PRE_NMS / TI) * NBATCH), 256, 0, stream>>>(boxes, areas, maskp);
    scan_kernel   <<<dim3(NBATCH), 64, 0, stream>>>(maskp, validm, boxes, flags, ccnt, out);
    (void)in_sizes; (void)n_in; (void)ws_size;
}

// Round 8
// 405.900 us; speedup vs baseline: 3.6941x; 1.1061x over previous
//
#include <hip/hip_runtime.h>
#include <cstdint>
#include <cmath>

#define NBATCH   8
#define NPB      500000
#define PRE_NMS  6000
#define POST_NMS 1000
#define NWORDS   94          // ceil(6000/64)
#define NBINS    16384       // 14-bit float prefix (sign+exp+5 mantissa)
#define CANDCAP  8192        // candidate cap per batch (expected ~6800 worst case)
#define BBOX_CLIP 4.135166556742356f   // log(1000/16)
#define NMS_THR  0.7f
#define TI 8                 // mask rows per block
#define TJ 512               // mask j-tile staged in LDS
#define WIN 16               // scan window (64 % WIN == 0: window never straddles words)
#define CNT_PAD 64           // counter stride in uints (256 B): one cache line per batch
#define SORT_CHUNK 2048      // bitonic phases k<=2048 are chunk-local -> parallel blocks

#define F_SORT 1u
#define F_COMP 2u
#define F_OOB  4u

// monotone map: ascending uint <=> ascending float
__device__ __forceinline__ unsigned monot(float f) {
    unsigned b = __float_as_uint(f);
    return (b & 0x80000000u) ? ~b : (b | 0x80000000u);
}

// ---------------- Phase 1a: 16384-bin histogram of key prefix ----------------
__global__ __launch_bounds__(256) void hist_kernel(const float* __restrict__ obj,
                                                   unsigned* __restrict__ hist) {
    __shared__ unsigned lh[NBINS];   // 64 KiB
    const int b = blockIdx.y;
    for (int q = threadIdx.x; q < NBINS; q += 256) lh[q] = 0;
    __syncthreads();
    const float* p = obj + (size_t)b * NPB;
    const int stride = gridDim.x * 256;
    for (int i = blockIdx.x * 256 + threadIdx.x; i < NPB; i += stride) {
        unsigned u = monot(p[i]);
        atomicAdd(&lh[u >> 18], 1u);
    }
    __syncthreads();
    unsigned* gh = hist + (size_t)b * NBINS;
    for (int q = threadIdx.x; q < NBINS; q += 256) {
        unsigned v = lh[q];
        if (v) atomicAdd(&gh[q], v);
    }
}

// ------- Phase 1b: find threshold bin (descending cumulative >= 6000) -------
__global__ __launch_bounds__(256) void thresh_kernel(const unsigned* __restrict__ hist,
                                                     unsigned* __restrict__ tbin) {
    __shared__ unsigned part[256], pre[256];
    const int b = blockIdx.x;
    const unsigned* gh = hist + (size_t)b * NBINS;
    const int t = threadIdx.x;
    const int PER = NBINS / 256;     // 64 bins per thread
    unsigned s = 0;
    for (int d = 0; d < PER; ++d) s += gh[NBINS - 1 - (t * PER + d)];
    part[t] = s;
    __syncthreads();
    if (t == 0) {
        unsigned run = 0;
        for (int q = 0; q < 256; ++q) { pre[q] = run; run += part[q]; }
    }
    __syncthreads();
    unsigned c = pre[t];
    if (c < PRE_NMS && c + part[t] >= PRE_NMS) {
        unsigned run = c;
        for (int d = 0; d < PER; ++d) {
            int bin = NBINS - 1 - (t * PER + d);
            run += gh[bin];
            if (run >= PRE_NMS) { tbin[b] = (unsigned)bin; break; }
        }
    }
}

// ------ Phase 1c: compact candidates — WAVE-AGGREGATED atomics --------------
__global__ __launch_bounds__(256) void compact_kernel(const float* __restrict__ obj,
                                                      const unsigned* __restrict__ tbin,
                                                      unsigned long long* __restrict__ cand,
                                                      unsigned* __restrict__ ccnt) {
    const int b = blockIdx.y;
    const unsigned T = tbin[b];
    const float* p = obj + (size_t)b * NPB;
    unsigned long long* cb = cand + (size_t)b * CANDCAP;
    const int lane = threadIdx.x & 63;
    const int stride = gridDim.x * 256;
    for (int i = blockIdx.x * 256 + threadIdx.x; i < NPB; i += stride) {
        unsigned u = monot(p[i]);
        const bool pred = (u >> 18) >= T;
        unsigned long long bal = __ballot(pred);
        if (bal == 0) continue;                      // common case: skip
        unsigned base = 0;
        // lane 0 has the smallest i in the wave -> active whenever any lane is
        if (lane == 0) base = atomicAdd(&ccnt[(size_t)b * CNT_PAD], __popcll(bal));
        base = (unsigned)__shfl((int)base, 0);
        if (pred) {
            unsigned pos = base + (unsigned)__popcll(bal & ((1ULL << lane) - 1ULL));
            if (pos < CANDCAP)  // composite: value desc, then index asc (via ~i)
                cb[pos] = ((unsigned long long)u << 32) | (unsigned)(~i);
        }
    }
}

// ---- Phase 1d-i: bitonic phases k=2..2048 — chunk-local, 32 parallel blocks -
// Partner ii^j stays inside the aligned 2048-chunk for all k<=2048 (j<=1024).
// Direction bit: k<=1024 -> (local ii & k); k=2048 -> chunk parity. Exactly
// reproduces the monolithic network's comparators -> bit-identical result.
__global__ __launch_bounds__(512) void sort_local_kernel(unsigned long long* __restrict__ cand) {
    __shared__ unsigned long long s[SORT_CHUNK];  // 16 KiB
    const int blk = blockIdx.x;
    const int b = blk >> 2, c = blk & 3;          // 4 chunks per batch
    unsigned long long* cb = cand + (size_t)b * CANDCAP + (size_t)c * SORT_CHUNK;
    const int t = threadIdx.x;
    for (int i = t; i < SORT_CHUNK; i += 512) s[i] = cb[i];
    __syncthreads();
    for (unsigned k = 2; k <= SORT_CHUNK; k <<= 1) {
        const bool kfull = (k == SORT_CHUNK);
        const bool upfull = (c & 1) == 0;         // global bit 11 == chunk parity
        for (unsigned j = k >> 1; j > 0; j >>= 1) {
            for (unsigned ii = t; ii < SORT_CHUNK; ii += 512) {
                unsigned l = ii ^ j;
                if (l > ii) {
                    unsigned long long a = s[ii], d = s[l];
                    bool up = kfull ? upfull : ((ii & k) == 0);
                    if (up ? (a < d) : (a > d)) { s[ii] = d; s[l] = a; }
                }
            }
            __syncthreads();
        }
    }
    for (int i = t; i < SORT_CHUNK; i += 512) cb[i] = s[i];
}

// ---- Phase 1d-ii: bitonic merge k=4096,8192 (25 passes) + checks + emit ----
__global__ __launch_bounds__(1024) void sort_merge_kernel(const unsigned long long* __restrict__ cand,
                                                          const float* __restrict__ obj,
                                                          unsigned* __restrict__ topk,
                                                          unsigned* __restrict__ flags) {
    __shared__ unsigned long long s[CANDCAP];  // 64 KiB
    const int b = blockIdx.x, t = threadIdx.x;
    const unsigned long long* cb = cand + (size_t)b * CANDCAP;
    for (int i = t; i < CANDCAP; i += 1024) s[i] = cb[i];
    __syncthreads();
    for (unsigned k = 2 * SORT_CHUNK; k <= CANDCAP; k <<= 1) {
        for (unsigned j = k >> 1; j > 0; j >>= 1) {
            for (unsigned ii = t; ii < CANDCAP; ii += 1024) {
                unsigned l = ii ^ j;
                if (l > ii) {
                    unsigned long long a = s[ii], c = s[l];
                    bool up = (ii & k) == 0;
                    if (up ? (a < c) : (a > c)) { s[ii] = c; s[l] = a; }
                }
            }
            __syncthreads();
        }
    }
    // ---- checks + emit ----
    unsigned f = 0;
    for (int r = t; r < PRE_NMS; r += 1024) {
        unsigned long long c = s[r];
        unsigned idx = ~(unsigned)(c & 0xffffffffULL);
        if (idx >= NPB) { f |= F_OOB; idx = 0; }
        else if (monot(obj[(size_t)b * NPB + idx]) != (unsigned)(c >> 32)) f |= F_COMP;
        if (r < PRE_NMS - 1 && !(c > s[r + 1])) f |= F_SORT;
        topk[(size_t)b * PRE_NMS + r] = idx;
    }
    if (f) atomicOr(&flags[b], f);
}

// ---------------- Phase 2: decode + clip + valid (numerics FROZEN) ----------
__global__ __launch_bounds__(256) void decode_kernel(const float* __restrict__ anchors,
                                                     const float* __restrict__ deltas,
                                                     const unsigned* __restrict__ topk,
                                                     const int* __restrict__ imh,
                                                     const int* __restrict__ imw,
                                                     float* __restrict__ boxes,
                                                     float* __restrict__ areas,
                                                     unsigned long long* __restrict__ validm) {
    const int b = blockIdx.y;
    const int r = blockIdx.x * 256 + threadIdx.x;
    const bool active = r < PRE_NMS;
    int vh = imh[0], vw = imw[0];
    float ih = (vh > 0 && vh < (1 << 20)) ? (float)vh : __int_as_float(vh);
    float iw = (vw > 0 && vw < (1 << 20)) ? (float)vw : __int_as_float(vw);
    bool valid = false;
    if (active) {
        unsigned idx = topk[(size_t)b * PRE_NMS + r];
        if (idx >= NPB) idx = 0;   // canary will have fired; avoid OOB
        const float4 a = ((const float4*)anchors)[(size_t)b * NPB + idx];
        const float4 d = ((const float4*)deltas)[(size_t)b * NPB + idx];
        float wa = a.z - a.x, ha = a.w - a.y;
        float cxa = a.x + 0.5f * wa, cya = a.y + 0.5f * ha;  // 0.5*x exact: fma-safe
        float dw = fminf(d.z, BBOX_CLIP), dh = fminf(d.w, BBOX_CLIP);
        float cx = __fadd_rn(__fmul_rn(d.x, wa), cxa);
        float cy = __fadd_rn(__fmul_rn(d.y, ha), cya);
        float ew = (float)::exp((double)dw), eh = (float)::exp((double)dh);
        float w = __fmul_rn(ew, wa), h = __fmul_rn(eh, ha);
        float x1 = cx - 0.5f * w, y1 = cy - 0.5f * h;
        float x2 = cx + 0.5f * w, y2 = cy + 0.5f * h;
        x1 = fminf(fmaxf(x1, 0.f), iw); y1 = fminf(fmaxf(y1, 0.f), ih);
        x2 = fminf(fmaxf(x2, 0.f), iw); y2 = fminf(fmaxf(y2, 0.f), ih);
        valid = (x2 - x1 >= 1.0f) && (y2 - y1 >= 1.0f);
        ((float4*)boxes)[(size_t)b * PRE_NMS + r] = make_float4(x1, y1, x2, y2);
        areas[(size_t)b * PRE_NMS + r] = __fmul_rn(x2 - x1, y2 - y1);
    }
    unsigned long long bal = __ballot(valid);
    int w = r >> 6;
    if ((threadIdx.x & 63) == 0 && w < NWORDS) validm[(size_t)b * NWORDS + w] = bal;
}

// ------- Phase 3: suppression bitmask, UPPER-TRIANGLE words only -----------
__global__ __launch_bounds__(256) void mask_kernel(const float* __restrict__ boxes,
                                                   const float* __restrict__ areas,
                                                   unsigned long long* __restrict__ mask) {
    __shared__ float4 sb[TJ];
    __shared__ float  sa[TJ];
    const int b = blockIdx.x & 7;            // XCD pin: block -> XCD round-robin
    const int i0 = (blockIdx.x >> 3) * TI;
    const int jbase = (i0 >> 6) << 6;
    const int wv = threadIdx.x >> 6, ln = threadIdx.x & 63;
    const int ia = i0 + 2 * wv, ic = ia + 1;  // 2 rows per wave; 6000 % 8 == 0
    const float4 bA = ((const float4*)boxes)[(size_t)b * PRE_NMS + ia];
    const float4 bC = ((const float4*)boxes)[(size_t)b * PRE_NMS + ic];
    const float aA = areas[(size_t)b * PRE_NMS + ia];
    const float aC = areas[(size_t)b * PRE_NMS + ic];
    unsigned long long* rowA = mask + ((size_t)b * PRE_NMS + ia) * NWORDS;
    unsigned long long* rowC = mask + ((size_t)b * PRE_NMS + ic) * NWORDS;
    const int wA = ia >> 6, wC = ic >> 6;
    for (int t0 = jbase; t0 < NWORDS * 64; t0 += TJ) {
        for (int e = threadIdx.x; e < TJ; e += 256) {
            int j = t0 + e;
            if (j < PRE_NMS) {
                sb[e] = ((const float4*)boxes)[(size_t)b * PRE_NMS + j];
                sa[e] = areas[(size_t)b * PRE_NMS + j];
            } else { sb[e] = make_float4(0.f, 0.f, 0.f, 0.f); sa[e] = 0.f; }
        }
        __syncthreads();
        for (int wl = 0; wl < TJ / 64; ++wl) {
            const int w = (t0 >> 6) + wl;
            if (w >= NWORDS) break;
            const int e = wl * 64 + ln;
            const int j = t0 + e;
            const float4 bj = sb[e];
            const float aj = sa[e];
            bool pA = false, pC = false;
            if (j < PRE_NMS) {   // EXACT same fp sequence as the passing round-3 kernel
                float xx1 = fmaxf(bA.x, bj.x), yy1 = fmaxf(bA.y, bj.y);
                float xx2 = fminf(bA.z, bj.z), yy2 = fminf(bA.w, bj.w);
                float inter = __fmul_rn(fmaxf(__fsub_rn(xx2, xx1), 0.f),
                                        fmaxf(__fsub_rn(yy2, yy1), 0.f));
                float den = __fadd_rn(__fsub_rn(__fadd_rn(aA, aj), inter), 1e-9f);
                pA = (j > ia) && (__fdiv_rn(inter, den) > NMS_THR);
                xx1 = fmaxf(bC.x, bj.x); yy1 = fmaxf(bC.y, bj.y);
                xx2 = fminf(bC.z, bj.z); yy2 = fminf(bC.w, bj.w);
                inter = __fmul_rn(fmaxf(__fsub_rn(xx2, xx1), 0.f),
                                  fmaxf(__fsub_rn(yy2, yy1), 0.f));
                den = __fadd_rn(__fsub_rn(__fadd_rn(aC, aj), inter), 1e-9f);
                pC = (j > ic) && (__fdiv_rn(inter, den) > NMS_THR);
            }
            unsigned long long mA = __ballot(pA), mC = __ballot(pC);
            if (ln == 0) {
                if (w >= wA) rowA[w] = mA;   // only own-diagonal-and-above words
                if (w >= wC) rowC[w] = mC;
            }
        }
        __syncthreads();
    }
}

// ------- Phase 4: windowed scan v3 — depth-3 pipeline, dwordx4 rows ---------
__global__ __launch_bounds__(64) void scan_kernel(const unsigned long long* __restrict__ mask,
                                                  const unsigned long long* __restrict__ validm,
                                                  const float* __restrict__ boxes,
                                                  const unsigned* __restrict__ flags,
                                                  const unsigned* __restrict__ ccnt,
                                                  float* __restrict__ out) {
    const int b = blockIdx.x, lane = threadIdx.x;
    const unsigned long long* mb = mask + (size_t)b * PRE_NMS * NWORDS;
    const int w0 = 2 * lane, w1 = 2 * lane + 1;
    unsigned long long r_lo = (w0 < NWORDS) ? ~validm[(size_t)b * NWORDS + w0] : ~0ULL;
    unsigned long long r_hi = (w1 < NWORDS) ? ~validm[(size_t)b * NWORDS + w1] : ~0ULL;
    int count = 0;

    uint4 MA[WIN], MB[WIN], MC[WIN];
    unsigned long long WA[WIN], WB[WIN], WC[WIN];
    float4 bxA, bxB, bxC;

#define ISSUE(M, W, BX, base_)                                                   \
    {                                                                            \
        const int bb_ = (base_);                                                 \
        const char* rb_ = (const char*)(mb + (size_t)bb_ * NWORDS);              \
        const int wI_ = bb_ >> 6;                                                \
        _Pragma("unroll")                                                        \
        for (int q = 0; q < WIN; ++q) {                                          \
            const char* rp_ = rb_ + (size_t)q * (NWORDS * 8);                    \
            M[q] = *(const uint4*)(rp_ + (size_t)lane * 16);                     \
            W[q] = *(const unsigned long long*)(rp_ + (size_t)wI_ * 8);          \
        }                                                                        \
        BX = (lane < WIN)                                                        \
                 ? ((const float4*)boxes)[(size_t)b * PRE_NMS + bb_ + lane]      \
                 : make_float4(0.f, 0.f, 0.f, 0.f);                              \
    }

#define RESOLVE(M, W, BX, base_)                                                 \
    {                                                                            \
        const int bb_ = (base_);                                                 \
        const int wR_ = bb_ >> 6, s0_ = bb_ & 63;                                \
        const unsigned long long sel_ = (wR_ & 1) ? r_hi : r_lo;                 \
        const int srcl_ = wR_ >> 1;                                              \
        const unsigned lo_ = (unsigned)__shfl((int)(unsigned)(sel_ & 0xffffffffULL), srcl_); \
        const unsigned hi_ = (unsigned)__shfl((int)(unsigned)(sel_ >> 32), srcl_);           \
        const unsigned long long ww_ = ((unsigned long long)hi_ << 32) | lo_;    \
        unsigned cand_ = (unsigned)((~ww_) >> s0_) & 0xFFFFu;                    \
        unsigned kept_ = 0;                                                      \
        const int cb_ = count;                                                   \
        _Pragma("unroll")                                                        \
        for (int q = 0; q < WIN; ++q) {                                          \
            if (((cand_ >> q) & 1u) && count < POST_NMS) {                       \
                kept_ |= 1u << q; ++count;                                       \
                cand_ &= ~(unsigned)(W[q] >> s0_);                               \
            }                                                                    \
        }                                                                        \
        const bool v0_ = (w0 >= wR_), v1_ = (w1 >= wR_);                         \
        _Pragma("unroll")                                                        \
        for (int q = 0; q < WIN; ++q) {                                          \
            if (kept_ & (1u << q)) {                                             \
                const uint4 m_ = M[q];                                           \
                if (v0_) r_lo |= ((unsigned long long)m_.y << 32) | m_.x;        \
                if (v1_) r_hi |= ((unsigned long long)m_.w << 32) | m_.z;        \
            }                                                                    \
        }                                                                        \
        if (lane < WIN && (kept_ & (1u << lane))) {                              \
            const int rank_ = cb_ + __popc(kept_ & ((1u << lane) - 1u));         \
            ((float4*)out)[(size_t)b * POST_NMS + rank_] = BX;                   \
        }                                                                        \
    }

    ISSUE(MA, WA, bxA, 0)
    ISSUE(MB, WB, bxB, WIN)
    bool done = false;
    for (int base = 0; base < PRE_NMS && !done; base += 3 * WIN) {
        const int n2 = base + 2 * WIN;
        ISSUE(MC, WC, bxC, (n2 < PRE_NMS) ? n2 : 0)
        RESOLVE(MA, WA, bxA, base)
        done = (count >= POST_NMS);
        if (!done) {
            const int n3 = base + 3 * WIN;
            ISSUE(MA, WA, bxA, (n3 < PRE_NMS) ? n3 : 0)
            RESOLVE(MB, WB, bxB, base + WIN)
            done = (count >= POST_NMS);
        }
        if (!done) {
            const int n4 = base + 4 * WIN;
            ISSUE(MB, WB, bxB, (n4 < PRE_NMS) ? n4 : 0)
            RESOLVE(MC, WC, bxC, base + 2 * WIN)
            done = (count >= POST_NMS);
        }
    }
#undef ISSUE
#undef RESOLVE

    // merged finalize: canary on invariant violation (absmax names the stage)
    if (lane == 0) {
        float canary = 0.f;
        const unsigned cc = ccnt[(size_t)b * CNT_PAD];
        const unsigned fl = flags[b];
        if (cc > CANDCAP)       canary = 111000.f;
        else if (cc < PRE_NMS)  canary = 222000.f;
        if (fl & F_SORT)        canary = 333000.f;
        if (fl & F_COMP)        canary = 444000.f;
        if (fl & F_OOB)         canary = 777000.f;
        if (canary != 0.f) out[(size_t)b * POST_NMS * 4] = canary;
    }
}

extern "C" void kernel_launch(void* const* d_in, const int* in_sizes, int n_in,
                              void* d_out, int out_size, void* d_ws, size_t ws_size,
                              hipStream_t stream) {
    const float* anchors = (const float*)d_in[0];
    const float* obj     = (const float*)d_in[1];
    const float* deltas  = (const float*)d_in[2];
    const int*   imh     = (const int*)d_in[3];
    const int*   imw     = (const int*)d_in[4];
    float* out = (float*)d_out;
    char* ws = (char*)d_ws;

    size_t off = 0;
    auto alloc = [&](size_t bytes) {
        size_t o = off;
        off = (off + bytes + 511) & ~(size_t)511;
        return o;
    };
    // regions needing zero-init FIRST and contiguous -> single memset
    const size_t HIST  = alloc((size_t)NBATCH * NBINS * 4);
    const size_t TBIN  = alloc((size_t)NBATCH * 4);
    const size_t CCNT  = alloc((size_t)NBATCH * CNT_PAD * 4);
    const size_t FLAGS = alloc((size_t)NBATCH * 4);
    const size_t CAND  = alloc((size_t)NBATCH * CANDCAP * 8);
    const size_t ZEND  = off;
    const size_t TOPK  = alloc((size_t)NBATCH * PRE_NMS * 4);
    const size_t BOX   = alloc((size_t)NBATCH * PRE_NMS * 16);
    const size_t AREA  = alloc((size_t)NBATCH * PRE_NMS * 4);
    const size_t VALID = alloc((size_t)NBATCH * NWORDS * 8);
    const size_t MASK  = alloc((size_t)NBATCH * PRE_NMS * NWORDS * 8);
    (void)alloc(1024);   // pad: scan's dwordx4 row reads overrun rows by <=272B
    if (ws_size < off) return;

    unsigned*            hist   = (unsigned*)(ws + HIST);
    unsigned*            tbin   = (unsigned*)(ws + TBIN);
    unsigned*            ccnt   = (unsigned*)(ws + CCNT);
    unsigned*            flags  = (unsigned*)(ws + FLAGS);
    unsigned long long*  cand   = (unsigned long long*)(ws + CAND);
    unsigned*            topk   = (unsigned*)(ws + TOPK);
    float*               boxes  = (float*)(ws + BOX);
    float*               areas  = (float*)(ws + AREA);
    unsigned long long*  validm = (unsigned long long*)(ws + VALID);
    unsigned long long*  maskp  = (unsigned long long*)(ws + MASK);

    hipMemsetAsync(ws, 0, ZEND, stream);   // hist+tbin+ccnt+flags+cand in one node
    hipMemsetAsync(out, 0, (size_t)out_size * sizeof(float), stream);

    hist_kernel      <<<dim3(32, NBATCH), 256, 0, stream>>>(obj, hist);
    thresh_kernel    <<<dim3(NBATCH), 256, 0, stream>>>(hist, tbin);
    compact_kernel   <<<dim3(128, NBATCH), 256, 0, stream>>>(obj, tbin, cand, ccnt);
    sort_local_kernel<<<dim3(NBATCH * (CANDCAP / SORT_CHUNK)), 512, 0, stream>>>(cand);
    sort_merge_kernel<<<dim3(NBATCH), 1024, 0, stream>>>(cand, obj, topk, flags);
    decode_kernel    <<<dim3((PRE_NMS + 255) / 256, NBATCH), 256, 0, stream>>>(
        anchors, deltas, topk, imh, imw, boxes, areas, validm);
    mask_kernel      <<<dim3((PRE_NMS / TI) * NBATCH), 256, 0, stream>>>(boxes, areas, maskp);
    scan_kernel      <<<dim3(NBATCH), 64, 0, stream>>>(maskp, validm, boxes, flags, ccnt, out);
    (void)in_sizes; (void)n_in; (void)ws_size;
}

// Round 9
// 379.196 us; speedup vs baseline: 3.9542x; 1.0704x over previous
//
#include <hip/hip_runtime.h>
#include <cstdint>
#include <cmath>

#define NBATCH   8
#define NPB      500000
#define PRE_NMS  6000
#define POST_NMS 1000
#define NWORDS   94          // ceil(6000/64)
#define NBINS    16384       // 14-bit float prefix (sign+exp+5 mantissa)
#define CANDCAP  8192        // candidate cap per batch (expected ~6800 worst case)
#define BBOX_CLIP 4.135166556742356f   // log(1000/16)
#define TI 16                // mask rows per block (4 per wave)
#define TJ 512               // mask j-tile staged in LDS
#define WIN 16               // scan window (64 % WIN == 0: window never straddles words)
#define CNT_PAD 64           // counter stride in uints (256 B): one cache line per batch
#define SORT_CHUNK 2048      // bitonic phases k<=2048 are chunk-local -> parallel blocks

#define F_SORT 1u
#define F_COMP 2u
#define F_OOB  4u

// monotone map: ascending uint <=> ascending float
__device__ __forceinline__ unsigned monot(float f) {
    unsigned b = __float_as_uint(f);
    return (b & 0x80000000u) ? ~b : (b | 0x80000000u);
}

// EXACT replacement for (__fdiv_rn(inter,den) > 0.7f), den > 0:
//   q > 0.7f  <=>  inter/den >= m,  m = 0.7f + 2^-25 (RN midpoint; the tie
//   rounds to 0x3F333334 which is even and > 0.7f, so boundary is >=).
//   m has 25 sig bits, den 24 -> m*(double)den exact (49-bit product);
//   comparison in double is therefore the exact reference predicate.
__device__ __forceinline__ bool iou_gt_thr(float inter, float den) {
    const double MID = (double)0.7f + 0x1p-25;
    return (double)inter >= MID * (double)den;
}

// ---------------- Phase 1a: 16384-bin histogram of key prefix ----------------
__global__ __launch_bounds__(256) void hist_kernel(const float* __restrict__ obj,
                                                   unsigned* __restrict__ hist) {
    __shared__ unsigned lh[NBINS];   // 64 KiB
    const int b = blockIdx.y;
    for (int q = threadIdx.x; q < NBINS; q += 256) lh[q] = 0;
    __syncthreads();
    const float* p = obj + (size_t)b * NPB;
    const int stride = gridDim.x * 256;
    for (int i = blockIdx.x * 256 + threadIdx.x; i < NPB; i += stride) {
        unsigned u = monot(p[i]);
        atomicAdd(&lh[u >> 18], 1u);
    }
    __syncthreads();
    unsigned* gh = hist + (size_t)b * NBINS;
    for (int q = threadIdx.x; q < NBINS; q += 256) {
        unsigned v = lh[q];
        if (v) atomicAdd(&gh[q], v);
    }
}

// ------- Phase 1b: find threshold bin (descending cumulative >= 6000) -------
__global__ __launch_bounds__(256) void thresh_kernel(const unsigned* __restrict__ hist,
                                                     unsigned* __restrict__ tbin) {
    __shared__ unsigned part[256], pre[256];
    const int b = blockIdx.x;
    const unsigned* gh = hist + (size_t)b * NBINS;
    const int t = threadIdx.x;
    const int PER = NBINS / 256;     // 64 bins per thread
    unsigned s = 0;
    for (int d = 0; d < PER; ++d) s += gh[NBINS - 1 - (t * PER + d)];
    part[t] = s;
    __syncthreads();
    if (t == 0) {
        unsigned run = 0;
        for (int q = 0; q < 256; ++q) { pre[q] = run; run += part[q]; }
    }
    __syncthreads();
    unsigned c = pre[t];
    if (c < PRE_NMS && c + part[t] >= PRE_NMS) {
        unsigned run = c;
        for (int d = 0; d < PER; ++d) {
            int bin = NBINS - 1 - (t * PER + d);
            run += gh[bin];
            if (run >= PRE_NMS) { tbin[b] = (unsigned)bin; break; }
        }
    }
}

// ------ Phase 1c: compact candidates — WAVE-AGGREGATED atomics --------------
__global__ __launch_bounds__(256) void compact_kernel(const float* __restrict__ obj,
                                                      const unsigned* __restrict__ tbin,
                                                      unsigned long long* __restrict__ cand,
                                                      unsigned* __restrict__ ccnt) {
    const int b = blockIdx.y;
    const unsigned T = tbin[b];
    const float* p = obj + (size_t)b * NPB;
    unsigned long long* cb = cand + (size_t)b * CANDCAP;
    const int lane = threadIdx.x & 63;
    const int stride = gridDim.x * 256;
    for (int i = blockIdx.x * 256 + threadIdx.x; i < NPB; i += stride) {
        unsigned u = monot(p[i]);
        const bool pred = (u >> 18) >= T;
        unsigned long long bal = __ballot(pred);
        if (bal == 0) continue;                      // common case: skip
        unsigned base = 0;
        // lane 0 has the smallest i in the wave -> active whenever any lane is
        if (lane == 0) base = atomicAdd(&ccnt[(size_t)b * CNT_PAD], __popcll(bal));
        base = (unsigned)__shfl((int)base, 0);
        if (pred) {
            unsigned pos = base + (unsigned)__popcll(bal & ((1ULL << lane) - 1ULL));
            if (pos < CANDCAP)  // composite: value desc, then index asc (via ~i)
                cb[pos] = ((unsigned long long)u << 32) | (unsigned)(~i);
        }
    }
}

// ---- Phase 1d-i: bitonic phases k=2..2048 — chunk-local, 32 parallel blocks -
__global__ __launch_bounds__(512) void sort_local_kernel(unsigned long long* __restrict__ cand) {
    __shared__ unsigned long long s[SORT_CHUNK];  // 16 KiB
    const int blk = blockIdx.x;
    const int b = blk >> 2, c = blk & 3;          // 4 chunks per batch
    unsigned long long* cb = cand + (size_t)b * CANDCAP + (size_t)c * SORT_CHUNK;
    const int t = threadIdx.x;
    for (int i = t; i < SORT_CHUNK; i += 512) s[i] = cb[i];
    __syncthreads();
    for (unsigned k = 2; k <= SORT_CHUNK; k <<= 1) {
        const bool kfull = (k == SORT_CHUNK);
        const bool upfull = (c & 1) == 0;         // global bit 11 == chunk parity
        for (unsigned j = k >> 1; j > 0; j >>= 1) {
            for (unsigned ii = t; ii < SORT_CHUNK; ii += 512) {
                unsigned l = ii ^ j;
                if (l > ii) {
                    unsigned long long a = s[ii], d = s[l];
                    bool up = kfull ? upfull : ((ii & k) == 0);
                    if (up ? (a < d) : (a > d)) { s[ii] = d; s[l] = a; }
                }
            }
            __syncthreads();
        }
    }
    for (int i = t; i < SORT_CHUNK; i += 512) cb[i] = s[i];
}

// ---- Phase 1d-ii: bitonic merge k=4096,8192 (25 passes) + checks + emit ----
__global__ __launch_bounds__(1024) void sort_merge_kernel(const unsigned long long* __restrict__ cand,
                                                          const float* __restrict__ obj,
                                                          unsigned* __restrict__ topk,
                                                          unsigned* __restrict__ flags) {
    __shared__ unsigned long long s[CANDCAP];  // 64 KiB
    const int b = blockIdx.x, t = threadIdx.x;
    const unsigned long long* cb = cand + (size_t)b * CANDCAP;
    for (int i = t; i < CANDCAP; i += 1024) s[i] = cb[i];
    __syncthreads();
    for (unsigned k = 2 * SORT_CHUNK; k <= CANDCAP; k <<= 1) {
        for (unsigned j = k >> 1; j > 0; j >>= 1) {
            for (unsigned ii = t; ii < CANDCAP; ii += 1024) {
                unsigned l = ii ^ j;
                if (l > ii) {
                    unsigned long long a = s[ii], c = s[l];
                    bool up = (ii & k) == 0;
                    if (up ? (a < c) : (a > c)) { s[ii] = c; s[l] = a; }
                }
            }
            __syncthreads();
        }
    }
    // ---- checks + emit ----
    unsigned f = 0;
    for (int r = t; r < PRE_NMS; r += 1024) {
        unsigned long long c = s[r];
        unsigned idx = ~(unsigned)(c & 0xffffffffULL);
        if (idx >= NPB) { f |= F_OOB; idx = 0; }
        else if (monot(obj[(size_t)b * NPB + idx]) != (unsigned)(c >> 32)) f |= F_COMP;
        if (r < PRE_NMS - 1 && !(c > s[r + 1])) f |= F_SORT;
        topk[(size_t)b * PRE_NMS + r] = idx;
    }
    if (f) atomicOr(&flags[b], f);
}

// ---------------- Phase 2: decode + clip + valid (numerics FROZEN) ----------
__global__ __launch_bounds__(256) void decode_kernel(const float* __restrict__ anchors,
                                                     const float* __restrict__ deltas,
                                                     const unsigned* __restrict__ topk,
                                                     const int* __restrict__ imh,
                                                     const int* __restrict__ imw,
                                                     float* __restrict__ boxes,
                                                     float* __restrict__ areas,
                                                     unsigned long long* __restrict__ validm) {
    const int b = blockIdx.y;
    const int r = blockIdx.x * 256 + threadIdx.x;
    const bool active = r < PRE_NMS;
    int vh = imh[0], vw = imw[0];
    float ih = (vh > 0 && vh < (1 << 20)) ? (float)vh : __int_as_float(vh);
    float iw = (vw > 0 && vw < (1 << 20)) ? (float)vw : __int_as_float(vw);
    bool valid = false;
    if (active) {
        unsigned idx = topk[(size_t)b * PRE_NMS + r];
        if (idx >= NPB) idx = 0;   // canary will have fired; avoid OOB
        const float4 a = ((const float4*)anchors)[(size_t)b * NPB + idx];
        const float4 d = ((const float4*)deltas)[(size_t)b * NPB + idx];
        float wa = a.z - a.x, ha = a.w - a.y;
        float cxa = a.x + 0.5f * wa, cya = a.y + 0.5f * ha;  // 0.5*x exact: fma-safe
        float dw = fminf(d.z, BBOX_CLIP), dh = fminf(d.w, BBOX_CLIP);
        float cx = __fadd_rn(__fmul_rn(d.x, wa), cxa);
        float cy = __fadd_rn(__fmul_rn(d.y, ha), cya);
        float ew = (float)::exp((double)dw), eh = (float)::exp((double)dh);
        float w = __fmul_rn(ew, wa), h = __fmul_rn(eh, ha);
        float x1 = cx - 0.5f * w, y1 = cy - 0.5f * h;
        float x2 = cx + 0.5f * w, y2 = cy + 0.5f * h;
        x1 = fminf(fmaxf(x1, 0.f), iw); y1 = fminf(fmaxf(y1, 0.f), ih);
        x2 = fminf(fmaxf(x2, 0.f), iw); y2 = fminf(fmaxf(y2, 0.f), ih);
        valid = (x2 - x1 >= 1.0f) && (y2 - y1 >= 1.0f);
        ((float4*)boxes)[(size_t)b * PRE_NMS + r] = make_float4(x1, y1, x2, y2);
        areas[(size_t)b * PRE_NMS + r] = __fmul_rn(x2 - x1, y2 - y1);
    }
    unsigned long long bal = __ballot(valid);
    int w = r >> 6;
    if ((threadIdx.x & 63) == 0 && w < NWORDS) validm[(size_t)b * NWORDS + w] = bal;
}

// ------- Phase 3: suppression bitmask — 4 rows/wave, div-free predicate -----
__global__ __launch_bounds__(256) void mask_kernel(const float* __restrict__ boxes,
                                                   const float* __restrict__ areas,
                                                   unsigned long long* __restrict__ mask) {
    __shared__ float4 sb[TJ];
    __shared__ float  sa[TJ];
    const int b = blockIdx.x & 7;            // XCD pin: block -> XCD round-robin
    const int i0 = (blockIdx.x >> 3) * TI;
    const int jbase = (i0 >> 6) << 6;
    const int wv = threadIdx.x >> 6, ln = threadIdx.x & 63;
    const int ir = i0 + 4 * wv;              // 4 rows per wave; 6000 % 16 == 0
    float4 bx[4]; float ar[4]; int wlo[4];
    unsigned long long* rowp[4];
#pragma unroll
    for (int r = 0; r < 4; ++r) {
        const int i = ir + r;
        bx[r]   = ((const float4*)boxes)[(size_t)b * PRE_NMS + i];
        ar[r]   = areas[(size_t)b * PRE_NMS + i];
        rowp[r] = mask + ((size_t)b * PRE_NMS + i) * NWORDS;
        wlo[r]  = i >> 6;
    }
    for (int t0 = jbase; t0 < NWORDS * 64; t0 += TJ) {
        for (int e = threadIdx.x; e < TJ; e += 256) {
            int j = t0 + e;
            if (j < PRE_NMS) {
                sb[e] = ((const float4*)boxes)[(size_t)b * PRE_NMS + j];
                sa[e] = areas[(size_t)b * PRE_NMS + j];
            } else { sb[e] = make_float4(0.f, 0.f, 0.f, 0.f); sa[e] = 0.f; }
        }
        __syncthreads();
        for (int wl = 0; wl < TJ / 64; ++wl) {
            const int w = (t0 >> 6) + wl;
            if (w >= NWORDS) break;
            const int e = wl * 64 + ln;
            const int j = t0 + e;
            const float4 bj = sb[e];
            const float aj = sa[e];
            const bool jin = (j < PRE_NMS);
#pragma unroll
            for (int r = 0; r < 4; ++r) {
                // EXACT same f32 sequence as the passing kernels up to the
                // divide; divide-compare replaced by the proven-equivalent
                // double midpoint comparison (see iou_gt_thr).
                float xx1 = fmaxf(bx[r].x, bj.x), yy1 = fmaxf(bx[r].y, bj.y);
                float xx2 = fminf(bx[r].z, bj.z), yy2 = fminf(bx[r].w, bj.w);
                float inter = __fmul_rn(fmaxf(__fsub_rn(xx2, xx1), 0.f),
                                        fmaxf(__fsub_rn(yy2, yy1), 0.f));
                float den = __fadd_rn(__fsub_rn(__fadd_rn(ar[r], aj), inter), 1e-9f);
                bool p = jin && (j > ir + r) && iou_gt_thr(inter, den);
                unsigned long long m = __ballot(p);
                if (ln == 0 && w >= wlo[r]) rowp[r][w] = m;
            }
        }
        __syncthreads();
    }
}

// ------- Phase 4: windowed scan v3 — depth-3 pipeline, dwordx4 rows ---------
__global__ __launch_bounds__(64) void scan_kernel(const unsigned long long* __restrict__ mask,
                                                  const unsigned long long* __restrict__ validm,
                                                  const float* __restrict__ boxes,
                                                  const unsigned* __restrict__ flags,
                                                  const unsigned* __restrict__ ccnt,
                                                  float* __restrict__ out) {
    const int b = blockIdx.x, lane = threadIdx.x;
    const unsigned long long* mb = mask + (size_t)b * PRE_NMS * NWORDS;
    const int w0 = 2 * lane, w1 = 2 * lane + 1;
    unsigned long long r_lo = (w0 < NWORDS) ? ~validm[(size_t)b * NWORDS + w0] : ~0ULL;
    unsigned long long r_hi = (w1 < NWORDS) ? ~validm[(size_t)b * NWORDS + w1] : ~0ULL;
    int count = 0;

    uint4 MA[WIN], MB[WIN], MC[WIN];
    unsigned long long WA[WIN], WB[WIN], WC[WIN];
    float4 bxA, bxB, bxC;

#define ISSUE(M, W, BX, base_)                                                   \
    {                                                                            \
        const int bb_ = (base_);                                                 \
        const char* rb_ = (const char*)(mb + (size_t)bb_ * NWORDS);              \
        const int wI_ = bb_ >> 6;                                                \
        _Pragma("unroll")                                                        \
        for (int q = 0; q < WIN; ++q) {                                          \
            const char* rp_ = rb_ + (size_t)q * (NWORDS * 8);                    \
            M[q] = *(const uint4*)(rp_ + (size_t)lane * 16);                     \
            W[q] = *(const unsigned long long*)(rp_ + (size_t)wI_ * 8);          \
        }                                                                        \
        BX = (lane < WIN)                                                        \
                 ? ((const float4*)boxes)[(size_t)b * PRE_NMS + bb_ + lane]      \
                 : make_float4(0.f, 0.f, 0.f, 0.f);                              \
    }

#define RESOLVE(M, W, BX, base_)                                                 \
    {                                                                            \
        const int bb_ = (base_);                                                 \
        const int wR_ = bb_ >> 6, s0_ = bb_ & 63;                                \
        const unsigned long long sel_ = (wR_ & 1) ? r_hi : r_lo;                 \
        const int srcl_ = wR_ >> 1;                                              \
        const unsigned lo_ = (unsigned)__shfl((int)(unsigned)(sel_ & 0xffffffffULL), srcl_); \
        const unsigned hi_ = (unsigned)__shfl((int)(unsigned)(sel_ >> 32), srcl_);           \
        const unsigned long long ww_ = ((unsigned long long)hi_ << 32) | lo_;    \
        unsigned cand_ = (unsigned)((~ww_) >> s0_) & 0xFFFFu;                    \
        unsigned kept_ = 0;                                                      \
        const int cb_ = count;                                                   \
        _Pragma("unroll")                                                        \
        for (int q = 0; q < WIN; ++q) {                                          \
            if (((cand_ >> q) & 1u) && count < POST_NMS) {                       \
                kept_ |= 1u << q; ++count;                                       \
                cand_ &= ~(unsigned)(W[q] >> s0_);                               \
            }                                                                    \
        }                                                                        \
        const bool v0_ = (w0 >= wR_), v1_ = (w1 >= wR_);                         \
        _Pragma("unroll")                                                        \
        for (int q = 0; q < WIN; ++q) {                                          \
            if (kept_ & (1u << q)) {                                             \
                const uint4 m_ = M[q];                                           \
                if (v0_) r_lo |= ((unsigned long long)m_.y << 32) | m_.x;        \
                if (v1_) r_hi |= ((unsigned long long)m_.w << 32) | m_.z;        \
            }                                                                    \
        }                                                                        \
        if (lane < WIN && (kept_ & (1u << lane))) {                              \
            const int rank_ = cb_ + __popc(kept_ & ((1u << lane) - 1u));         \
            ((float4*)out)[(size_t)b * POST_NMS + rank_] = BX;                   \
        }                                                                        \
    }

    ISSUE(MA, WA, bxA, 0)
    ISSUE(MB, WB, bxB, WIN)
    bool done = false;
    for (int base = 0; base < PRE_NMS && !done; base += 3 * WIN) {
        const int n2 = base + 2 * WIN;
        ISSUE(MC, WC, bxC, (n2 < PRE_NMS) ? n2 : 0)
        RESOLVE(MA, WA, bxA, base)
        done = (count >= POST_NMS);
        if (!done) {
            const int n3 = base + 3 * WIN;
            ISSUE(MA, WA, bxA, (n3 < PRE_NMS) ? n3 : 0)
            RESOLVE(MB, WB, bxB, base + WIN)
            done = (count >= POST_NMS);
        }
        if (!done) {
            const int n4 = base + 4 * WIN;
            ISSUE(MB, WB, bxB, (n4 < PRE_NMS) ? n4 : 0)
            RESOLVE(MC, WC, bxC, base + 2 * WIN)
            done = (count >= POST_NMS);
        }
    }
#undef ISSUE
#undef RESOLVE

    // merged finalize: canary on invariant violation (absmax names the stage)
    if (lane == 0) {
        float canary = 0.f;
        const unsigned cc = ccnt[(size_t)b * CNT_PAD];
        const unsigned fl = flags[b];
        if (cc > CANDCAP)       canary = 111000.f;
        else if (cc < PRE_NMS)  canary = 222000.f;
        if (fl & F_SORT)        canary = 333000.f;
        if (fl & F_COMP)        canary = 444000.f;
        if (fl & F_OOB)         canary = 777000.f;
        if (canary != 0.f) out[(size_t)b * POST_NMS * 4] = canary;
    }
}

extern "C" void kernel_launch(void* const* d_in, const int* in_sizes, int n_in,
                              void* d_out, int out_size, void* d_ws, size_t ws_size,
                              hipStream_t stream) {
    const float* anchors = (const float*)d_in[0];
    const float* obj     = (const float*)d_in[1];
    const float* deltas  = (const float*)d_in[2];
    const int*   imh     = (const int*)d_in[3];
    const int*   imw     = (const int*)d_in[4];
    float* out = (float*)d_out;
    char* ws = (char*)d_ws;

    size_t off = 0;
    auto alloc = [&](size_t bytes) {
        size_t o = off;
        off = (off + bytes + 511) & ~(size_t)511;
        return o;
    };
    // regions needing zero-init FIRST and contiguous -> single memset
    const size_t HIST  = alloc((size_t)NBATCH * NBINS * 4);
    const size_t TBIN  = alloc((size_t)NBATCH * 4);
    const size_t CCNT  = alloc((size_t)NBATCH * CNT_PAD * 4);
    const size_t FLAGS = alloc((size_t)NBATCH * 4);
    const size_t CAND  = alloc((size_t)NBATCH * CANDCAP * 8);
    const size_t ZEND  = off;
    const size_t TOPK  = alloc((size_t)NBATCH * PRE_NMS * 4);
    const size_t BOX   = alloc((size_t)NBATCH * PRE_NMS * 16);
    const size_t AREA  = alloc((size_t)NBATCH * PRE_NMS * 4);
    const size_t VALID = alloc((size_t)NBATCH * NWORDS * 8);
    const size_t MASK  = alloc((size_t)NBATCH * PRE_NMS * NWORDS * 8);
    (void)alloc(1024);   // pad: scan's dwordx4 row reads overrun rows by <=272B
    if (ws_size < off) return;

    unsigned*            hist   = (unsigned*)(ws + HIST);
    unsigned*            tbin   = (unsigned*)(ws + TBIN);
    unsigned*            ccnt   = (unsigned*)(ws + CCNT);
    unsigned*            flags  = (unsigned*)(ws + FLAGS);
    unsigned long long*  cand   = (unsigned long long*)(ws + CAND);
    unsigned*            topk   = (unsigned*)(ws + TOPK);
    float*               boxes  = (float*)(ws + BOX);
    float*               areas  = (float*)(ws + AREA);
    unsigned long long*  validm = (unsigned long long*)(ws + VALID);
    unsigned long long*  maskp  = (unsigned long long*)(ws + MASK);

    hipMemsetAsync(ws, 0, ZEND, stream);   // hist+tbin+ccnt+flags+cand in one node
    hipMemsetAsync(out, 0, (size_t)out_size * sizeof(float), stream);

    hist_kernel      <<<dim3(32, NBATCH), 256, 0, stream>>>(obj, hist);
    thresh_kernel    <<<dim3(NBATCH), 256, 0, stream>>>(hist, tbin);
    compact_kernel   <<<dim3(128, NBATCH), 256, 0, stream>>>(obj, tbin, cand, ccnt);
    sort_local_kernel<<<dim3(NBATCH * (CANDCAP / SORT_CHUNK)), 512, 0, stream>>>(cand);
    sort_merge_kernel<<<dim3(NBATCH), 1024, 0, stream>>>(cand, obj, topk, flags);
    decode_kernel    <<<dim3((PRE_NMS + 255) / 256, NBATCH), 256, 0, stream>>>(
        anchors, deltas, topk, imh, imw, boxes, areas, validm);
    mask_kernel      <<<dim3((PRE_NMS / TI) * NBATCH), 256, 0, stream>>>(boxes, areas, maskp);
    scan_kernel      <<<dim3(NBATCH), 64, 0, stream>>>(maskp, validm, boxes, flags, ccnt, out);
    (void)in_sizes; (void)n_in; (void)ws_size;
}